// Round 4
// baseline (952.575 us; speedup 1.0000x reference)
//
#include <hip/hip_runtime.h>
#include <hip/hip_bf16.h>

typedef __attribute__((ext_vector_type(4))) float f32x4;
typedef __attribute__((ext_vector_type(8))) short s16x8;

#define SEQ 2048
#define DM  2048
#define NH  16
#define HD  128

__device__ __forceinline__ unsigned short f2b(float f){
  unsigned int u = __builtin_bit_cast(unsigned int, f);
  u += 0x7fffu + ((u >> 16) & 1u);
  return (unsigned short)(u >> 16);
}
__device__ __forceinline__ float b2f(unsigned short h){
  unsigned int u = ((unsigned int)h) << 16;
  return __builtin_bit_cast(float, u);
}
__device__ __forceinline__ f32x4 mfma16(s16x8 a, s16x8 b, f32x4 c){
  return __builtin_amdgcn_mfma_f32_16x16x32_bf16(a, b, c, 0, 0, 0);
}

// ---------------------------------------------------------------------------
// One-shot f32 -> bf16 conversion: x -> xb, [wq|wk|wv] -> wfused, wo -> wob.
// ---------------------------------------------------------------------------
__global__ __launch_bounds__(256)
void convert_kernel(const float* __restrict__ x,  const float* __restrict__ wq,
                    const float* __restrict__ wk, const float* __restrict__ wv,
                    const float* __restrict__ wo,
                    unsigned short* __restrict__ xb,
                    unsigned short* __restrict__ wfused,
                    unsigned short* __restrict__ wob)
{
  size_t e = ((size_t)blockIdx.x * 256 + threadIdx.x) * 8;
  const float* src; unsigned short* dst;
  if (e < 16777216){ src = x + e; dst = xb + e; }
  else if (e < 29360128){
    size_t o = e - 16777216;
    int sel = (int)(o >> 22);
    const float* w = sel == 0 ? wq : (sel == 1 ? wk : wv);
    src = w + (o & 4194303); dst = wfused + o;
  } else {
    size_t o = e - 29360128;
    src = wo + o; dst = wob + o;
  }
  float4 a = ((const float4*)src)[0];
  float4 b = ((const float4*)src)[1];
  s16x8 v;
  v[0]=(short)f2b(a.x); v[1]=(short)f2b(a.y); v[2]=(short)f2b(a.z); v[3]=(short)f2b(a.w);
  v[4]=(short)f2b(b.x); v[5]=(short)f2b(b.y); v[6]=(short)f2b(b.z); v[7]=(short)f2b(b.w);
  *(s16x8*)dst = v;
}

// ---------------------------------------------------------------------------
// m97-structure GEMM: C[M][N] = A[M][K] * B[N][K]^T, bf16 MFMA, K=2048,
// 128x128 tile, BK=64, global_load_lds(16B) -> linear LDS, ds_read_b128.
// MODE 0: A=xb, B=wfused (6144 rows). Q/K cols: RoPE fused in epilogue ->
//         qr/kr bf16 (B,H,S,hd) + K f32 to d_out. V cols -> vout f32 + vt bf16.
// MODE 1: A=attnout bf16, B=wob -> outf f32.
// ---------------------------------------------------------------------------
template<int MODE>
__global__ __launch_bounds__(256)
void gemm_kernel(const unsigned short* __restrict__ A,
                 const unsigned short* __restrict__ B,
                 unsigned short* __restrict__ qr, unsigned short* __restrict__ kr,
                 float* __restrict__ koutf,
                 float* __restrict__ voutf, unsigned short* __restrict__ vt,
                 float* __restrict__ outf, const int* __restrict__ sp)
{
  const int tid  = threadIdx.x;
  const int lane = tid & 63;
  const int w    = tid >> 6;
  const int wr   = w >> 1, wc = w & 1;
  const int m0   = blockIdx.x * 128;
  const int n0   = blockIdx.y * 128;

  __shared__ unsigned short Alds[128 * 64];   // linear: row stride 128B
  __shared__ unsigned short Blds[128 * 64];

  f32x4 acc[4][4] = {};

  const unsigned short* Abase = A + (size_t)m0 * 2048;
  const unsigned short* Bbase = B + (size_t)n0 * 2048;
  const int rr = lane >> 3;          // 0..7
  const int cc = (lane & 7) * 8;     // element offset within 64-col chunk

  for (int k0 = 0; k0 < 2048; k0 += 64){
    __syncthreads();
    #pragma unroll
    for (int q = 0; q < 4; q++){
      int row = q*32 + w*8 + rr;
      __builtin_amdgcn_global_load_lds(
        (const __attribute__((address_space(1))) void*)(Abase + (size_t)row*2048 + k0 + cc),
        (__attribute__((address_space(3))) void*)((char*)Alds + q*4096 + w*1024),
        16, 0, 0);
      __builtin_amdgcn_global_load_lds(
        (const __attribute__((address_space(1))) void*)(Bbase + (size_t)row*2048 + k0 + cc),
        (__attribute__((address_space(3))) void*)((char*)Blds + q*4096 + w*1024),
        16, 0, 0);
    }
    __syncthreads();
    #pragma unroll
    for (int ks = 0; ks < 2; ks++){
      s16x8 af[4], bfr[4];
      const int kb = ks*64 + ((lane >> 4) << 4);   // byte offset within row
      #pragma unroll
      for (int i = 0; i < 4; i++){
        int r = wr*64 + i*16 + (lane & 15);
        af[i] = *(const s16x8*)((const char*)Alds + r*128 + kb);
      }
      #pragma unroll
      for (int j = 0; j < 4; j++){
        int r = wc*64 + j*16 + (lane & 15);
        bfr[j] = *(const s16x8*)((const char*)Blds + r*128 + kb);
      }
      #pragma unroll
      for (int i = 0; i < 4; i++)
        #pragma unroll
        for (int j = 0; j < 4; j++)
          acc[i][j] = mfma16(af[i], bfr[j], acc[i][j]);
    }
  }

  // ---- epilogue: C/D layout col=lane&15, row=(lane>>4)*4+reg ----
  const int col = lane & 15;
  const int rq  = (lane >> 4) << 2;

  if (MODE == 1){
    #pragma unroll
    for (int i = 0; i < 4; i++)
      #pragma unroll
      for (int j = 0; j < 4; j++)
        #pragma unroll
        for (int r = 0; r < 4; r++)
          outf[(size_t)(m0 + wr*64 + i*16 + rq + r) * DM + n0 + wc*64 + j*16 + col]
            = acc[i][j][r];
    return;
  }

  const int b = m0 >> 11;
  if (n0 < 4096){
    // ---- RoPE-fused Q/K epilogue ----
    const bool isK = (n0 >= 2048);
    unsigned short* dst = isK ? kr : qr;
    const int odd = lane & 1;
    const int sp0 = sp[0];
    const int nb  = n0 - (isK ? 2048 : 0);
    float fj[4];
    #pragma unroll
    for (int j = 0; j < 4; j++){
      int nn = nb + wc*64 + j*16 + col;
      fj[j] = exp2f(-(float)(nn >> 1) * (13.287712379549449f / 1024.0f));
    }
    #pragma unroll
    for (int i = 0; i < 4; i++){
      #pragma unroll
      for (int r = 0; r < 4; r++){
        int m = m0 + wr*64 + i*16 + rq + r;
        int s = m & 2047;
        float pos = (float)(sp0 + s);
        #pragma unroll
        for (int j = 0; j < 4; j++){
          float v  = acc[i][j][r];
          float vx = __shfl_xor(v, 1);
          float sn, cs;
          __sincosf(pos * fj[j], &sn, &cs);
          float x1 = odd ? vx : v;
          float x2 = odd ? v  : vx;
          float ov = odd ? (x1*sn + x2*cs) : (x1*cs - x2*sn);
          int nn = nb + wc*64 + j*16 + col;
          int c  = (nn >> 1) + (odd ? 1024 : 0);
          size_t adr = ((size_t)(b*NH + (c >> 7)) * SEQ + s) * HD + (c & 127);
          dst[adr] = f2b(ov);
          if (isK) koutf[adr] = ov;
        }
      }
    }
  } else {
    // ---- V epilogue: vout f32 (B,H,S,hd) + vt bf16 (B,H,hd,S) ----
    const int s_b = m0 & 2047;
    #pragma unroll
    for (int i = 0; i < 4; i++){
      int sb = s_b + wr*64 + i*16 + rq;
      #pragma unroll
      for (int j = 0; j < 4; j++){
        int d = (n0 - 4096) + wc*64 + j*16 + col;
        int h = d >> 7, dd = d & 127;
        size_t vbase = ((size_t)(b*NH + h) * SEQ + sb) * HD + dd;
        #pragma unroll
        for (int r = 0; r < 4; r++)
          voutf[vbase + (size_t)r * HD] = acc[i][j][r];
        ushort4 pk;
        pk.x = f2b(acc[i][j][0]); pk.y = f2b(acc[i][j][1]);
        pk.z = f2b(acc[i][j][2]); pk.w = f2b(acc[i][j][3]);
        *(ushort4*)(vt + ((size_t)(b*NH + h) * HD + dd) * SEQ + sb) = pk;
      }
    }
  }
}

// ---------------------------------------------------------------------------
// Causal flash attention, v2: block = 128 q-rows x one (b,h); 4 waves x 32
// rows; KVBLK=64. K 64x128 (rows 256B, swz (r&15)<<4), V^T 128x64 (rows 128B,
// swz (r&7)<<4), P per-wave 32x64 (rows 128B, swz (r&7)<<4). Heavy-first
// block order for causal load balance.
// ---------------------------------------------------------------------------
__global__ __launch_bounds__(256)
void attn_kernel(const unsigned short* __restrict__ qr,
                 const unsigned short* __restrict__ kr,
                 const unsigned short* __restrict__ vt,
                 unsigned short* __restrict__ attnout)
{
  const int qb   = (int)gridDim.x - 1 - (int)blockIdx.x;  // heavy blocks first
  const int bh   = blockIdx.y;          // 0..63
  const int tid  = threadIdx.x;
  const int lane = tid & 63;
  const int w    = tid >> 6;
  const int q0w  = qb*128 + w*32;       // wave's 32 q-rows

  __shared__ unsigned short Klds[64 * 128];   // 16KB
  __shared__ unsigned short Vlds[128 * 64];   // 16KB
  __shared__ unsigned short Plds[4][32 * 64]; // 16KB (per-wave 4KB)

  const int l15 = lane & 15;
  const int lhi = lane >> 4;            // 0..3
  const int rq  = lhi << 2;

  // Q fragments: qf[qt][c], row = q0w + qt*16 + l15, k = c*32 + lhi*8
  s16x8 qf[2][4];
  #pragma unroll
  for (int qt = 0; qt < 2; qt++){
    const unsigned short* qbase =
      qr + ((size_t)bh*SEQ + q0w + qt*16 + l15) * HD + lhi*8;
    #pragma unroll
    for (int c = 0; c < 4; c++) qf[qt][c] = *(const s16x8*)(qbase + c*32);
  }

  f32x4 o[2][8] = {};
  float mrow[2][4], lrow[2][4];
  #pragma unroll
  for (int qt = 0; qt < 2; qt++)
    #pragma unroll
    for (int r = 0; r < 4; r++){ mrow[qt][r] = -1e30f; lrow[qt][r] = 0.f; }

  unsigned short* pw = &Plds[w][0];
  const int ntiles = 2*qb + 2;

  for (int t = 0; t < ntiles; t++){
    const int kv0 = t * 64;
    __syncthreads();
    { // stage K tile (64 x 128 bf16, rows 256B)
      int r = tid & 63, c4 = tid >> 6;
      const unsigned short* src = kr + ((size_t)bh*SEQ + kv0 + r) * HD + c4*32;
      char* drow = (char*)Klds + r*256;
      int sw = (r & 15) << 4;
      #pragma unroll
      for (int k = 0; k < 4; k++)
        *(s16x8*)(drow + ((c4*64 + k*16) ^ sw)) = *(const s16x8*)(src + k*8);
    }
    { // stage V^T tile (128 x 64 bf16, rows 128B)
      int r = tid & 127, c2 = tid >> 7;
      const unsigned short* src = vt + ((size_t)bh*HD + r) * SEQ + kv0 + c2*32;
      char* drow = (char*)Vlds + r*128;
      int sw = (r & 7) << 4;
      #pragma unroll
      for (int k = 0; k < 4; k++)
        *(s16x8*)(drow + ((c2*64 + k*16) ^ sw)) = *(const s16x8*)(src + k*8);
    }
    __syncthreads();

    // ---- S = Q K^T : st[qt][j] covers rows qt*16, cols kv0 + j*16 ----
    f32x4 st[2][4];
    #pragma unroll
    for (int qt = 0; qt < 2; qt++)
      #pragma unroll
      for (int j = 0; j < 4; j++) st[qt][j] = (f32x4){0.f,0.f,0.f,0.f};
    #pragma unroll
    for (int j = 0; j < 4; j++){
      int krw = j*16 + l15;
      int sw  = (krw & 15) << 4;
      #pragma unroll
      for (int c = 0; c < 4; c++){
        s16x8 kf = *(const s16x8*)((const char*)Klds + krw*256 +
                     ((c*64 + (lhi << 4)) ^ sw));
        st[0][j] = mfma16(qf[0][c], kf, st[0][j]);
        st[1][j] = mfma16(qf[1][c], kf, st[1][j]);
      }
    }

    // ---- mask + scale ----
    const float sc = 0.08838834764831845f;  // 1/sqrt(128)
    #pragma unroll
    for (int qt = 0; qt < 2; qt++)
      #pragma unroll
      for (int j = 0; j < 4; j++)
        #pragma unroll
        for (int r = 0; r < 4; r++){
          int qrow = q0w + qt*16 + rq + r;
          int kvc  = kv0 + j*16 + l15;
          st[qt][j][r] = (kvc > qrow) ? -1e30f : st[qt][j][r] * sc;
        }

    // ---- online softmax (row spread across the 16 lanes of each quarter) --
    float mt[2][4], al[2][4], rs[2][4];
    #pragma unroll
    for (int qt = 0; qt < 2; qt++)
      #pragma unroll
      for (int r = 0; r < 4; r++)
        mt[qt][r] = fmaxf(fmaxf(st[qt][0][r], st[qt][1][r]),
                          fmaxf(st[qt][2][r], st[qt][3][r]));
    #pragma unroll
    for (int mk = 1; mk < 16; mk <<= 1)
      #pragma unroll
      for (int qt = 0; qt < 2; qt++)
        #pragma unroll
        for (int r = 0; r < 4; r++)
          mt[qt][r] = fmaxf(mt[qt][r], __shfl_xor(mt[qt][r], mk));
    #pragma unroll
    for (int qt = 0; qt < 2; qt++)
      #pragma unroll
      for (int r = 0; r < 4; r++){
        float mn = fmaxf(mrow[qt][r], mt[qt][r]);
        al[qt][r] = __expf(mrow[qt][r] - mn);
        mrow[qt][r] = mn;
        rs[qt][r] = 0.f;
      }
    // exp + write P (swizzled rows of 128B)
    #pragma unroll
    for (int qt = 0; qt < 2; qt++)
      #pragma unroll
      for (int r = 0; r < 4; r++){
        int prow = qt*16 + rq + r;
        char* prb = (char*)pw + prow*128;
        int sw = (prow & 7) << 4;
        #pragma unroll
        for (int j = 0; j < 4; j++){
          float p = __expf(st[qt][j][r] - mrow[qt][r]);
          rs[qt][r] += p;
          *(unsigned short*)(prb + (((j*16 + l15)*2) ^ sw)) = f2b(p);
        }
      }
    #pragma unroll
    for (int mk = 1; mk < 16; mk <<= 1)
      #pragma unroll
      for (int qt = 0; qt < 2; qt++)
        #pragma unroll
        for (int r = 0; r < 4; r++)
          rs[qt][r] += __shfl_xor(rs[qt][r], mk);
    #pragma unroll
    for (int qt = 0; qt < 2; qt++)
      #pragma unroll
      for (int r = 0; r < 4; r++)
        lrow[qt][r] = lrow[qt][r]*al[qt][r] + rs[qt][r];
    // rescale O
    #pragma unroll
    for (int qt = 0; qt < 2; qt++)
      #pragma unroll
      for (int c = 0; c < 8; c++)
        #pragma unroll
        for (int r = 0; r < 4; r++)
          o[qt][c][r] *= al[qt][r];

    asm volatile("s_waitcnt lgkmcnt(0)" ::: "memory");

    // ---- O += P V ----
    #pragma unroll
    for (int ks = 0; ks < 2; ks++){
      s16x8 pa[2];
      #pragma unroll
      for (int qt = 0; qt < 2; qt++){
        int prow = qt*16 + l15;
        pa[qt] = *(const s16x8*)((const char*)pw + prow*128 +
                   ((ks*64 + (lhi << 4)) ^ ((prow & 7) << 4)));
      }
      #pragma unroll
      for (int c = 0; c < 8; c++){
        int d = c*16 + l15;
        s16x8 vf = *(const s16x8*)((const char*)Vlds + d*128 +
                     ((ks*64 + (lhi << 4)) ^ ((d & 7) << 4)));
        o[0][c] = mfma16(pa[0], vf, o[0][c]);
        o[1][c] = mfma16(pa[1], vf, o[1][c]);
      }
    }
  }

  // ---- epilogue -> attn_out (B,S,D) bf16 ----
  const int b = bh >> 4, h = bh & 15;
  #pragma unroll
  for (int qt = 0; qt < 2; qt++)
    #pragma unroll
    for (int r = 0; r < 4; r++){
      float inv = 1.0f / lrow[qt][r];
      int s2 = q0w + qt*16 + rq + r;
      size_t base = ((size_t)(b*SEQ + s2)) * DM + h*HD;
      #pragma unroll
      for (int c = 0; c < 8; c++)
        attnout[base + c*16 + l15] = f2b(o[qt][c][r] * inv);
    }
}

// ---------------------------------------------------------------------------
extern "C" void kernel_launch(void* const* d_in, const int* in_sizes, int n_in,
                              void* d_out, int out_size, void* d_ws, size_t ws_size,
                              hipStream_t stream)
{
  const float* x  = (const float*)d_in[0];
  const float* wq = (const float*)d_in[1];
  const float* wk = (const float*)d_in[2];
  const float* wv = (const float*)d_in[3];
  const float* wo = (const float*)d_in[4];
  const int*   sp = (const int*)d_in[5];

  float* out  = (float*)d_out;            // (B,S,D) f32
  float* kout = out + 16777216;           // (B,H,S,hd) f32
  float* vout = out + 33554432;           // (B,H,S,hd) f32

  char* ws = (char*)d_ws;
  unsigned short* xb      = (unsigned short*)ws;                  // 8192x2048 bf16 (33.55MB)
  unsigned short* wfused  = (unsigned short*)(ws + 33554432);     // 6144x2048 bf16 (25.17MB)
  unsigned short* wob     = (unsigned short*)(ws + 58720256);     // 2048x2048 bf16 (8.39MB)
  unsigned short* qr      = (unsigned short*)(ws + 67108864);     // (B,H,S,hd) bf16
  unsigned short* kr      = (unsigned short*)(ws + 100663296);    // (B,H,S,hd) bf16
  unsigned short* vt      = (unsigned short*)(ws + 134217728);    // (B,H,hd,S) bf16
  unsigned short* attnout = (unsigned short*)ws;                  // alias xb (dead after GEMM1)

  // 1) f32 -> bf16 conversion of activations + weights
  convert_kernel<<<16384, 256, 0, stream>>>(x, wq, wk, wv, wo, xb, wfused, wob);
  // 2) fused QKV GEMM with RoPE epilogue
  gemm_kernel<0><<<dim3(64, 48), 256, 0, stream>>>(xb, wfused, qr, kr, kout,
                                                   vout, vt, nullptr, sp);
  // 3) causal flash attention (heavy-first)
  attn_kernel<<<dim3(16, 64), 256, 0, stream>>>(qr, kr, vt, attnout);
  // 4) output GEMM
  gemm_kernel<1><<<dim3(64, 16), 256, 0, stream>>>(attnout, wob, nullptr, nullptr,
                                                   nullptr, nullptr, nullptr, out, nullptr);
}

// Round 5
// 678.771 us; speedup vs baseline: 1.4034x; 1.4034x over previous
//
#include <hip/hip_runtime.h>
#include <hip/hip_bf16.h>

typedef __attribute__((ext_vector_type(4))) float f32x4;
typedef __attribute__((ext_vector_type(8))) short s16x8;

#define SEQ 2048
#define DM  2048
#define NH  16
#define HD  128

__device__ __forceinline__ unsigned short f2b(float f){
  unsigned int u = __builtin_bit_cast(unsigned int, f);
  u += 0x7fffu + ((u >> 16) & 1u);
  return (unsigned short)(u >> 16);
}
__device__ __forceinline__ float b2f(unsigned short h){
  unsigned int u = ((unsigned int)h) << 16;
  return __builtin_bit_cast(float, u);
}
__device__ __forceinline__ f32x4 mfma16(s16x8 a, s16x8 b, f32x4 c){
  return __builtin_amdgcn_mfma_f32_16x16x32_bf16(a, b, c, 0, 0, 0);
}

// ---------------------------------------------------------------------------
// One-shot f32 -> bf16 conversion: x -> xb, [wq|wk|wv] -> wfused, wo -> wob.
// ---------------------------------------------------------------------------
__global__ __launch_bounds__(256)
void convert_kernel(const float* __restrict__ x,  const float* __restrict__ wq,
                    const float* __restrict__ wk, const float* __restrict__ wv,
                    const float* __restrict__ wo,
                    unsigned short* __restrict__ xb,
                    unsigned short* __restrict__ wfused,
                    unsigned short* __restrict__ wob)
{
  size_t e = ((size_t)blockIdx.x * 256 + threadIdx.x) * 8;
  const float* src; unsigned short* dst;
  if (e < 16777216){ src = x + e; dst = xb + e; }
  else if (e < 29360128){
    size_t o = e - 16777216;
    int sel = (int)(o >> 22);
    const float* w = sel == 0 ? wq : (sel == 1 ? wk : wv);
    src = w + (o & 4194303); dst = wfused + o;
  } else {
    size_t o = e - 29360128;
    src = wo + o; dst = wob + o;
  }
  float4 a = ((const float4*)src)[0];
  float4 b = ((const float4*)src)[1];
  s16x8 v;
  v[0]=(short)f2b(a.x); v[1]=(short)f2b(a.y); v[2]=(short)f2b(a.z); v[3]=(short)f2b(a.w);
  v[4]=(short)f2b(b.x); v[5]=(short)f2b(b.y); v[6]=(short)f2b(b.z); v[7]=(short)f2b(b.w);
  *(s16x8*)dst = v;
}

// ---------------------------------------------------------------------------
// m97-structure GEMM: C[M][N] = A[M][K] * B[N][K]^T, bf16 MFMA, K=2048,
// 128x128 tile, BK=64, global_load_lds(16B) -> linear LDS, ds_read_b128.
// MODE 0: A=xb, B=wfused (6144 rows). Q/K cols: RoPE fused in epilogue ->
//         qr/kr bf16 (B,H,S,hd) + K f32 to d_out. V cols -> vout f32 + vt bf16.
// MODE 1: A=attnout bf16, B=wob -> outf f32.
// ---------------------------------------------------------------------------
template<int MODE>
__global__ __launch_bounds__(256)
void gemm_kernel(const unsigned short* __restrict__ A,
                 const unsigned short* __restrict__ B,
                 unsigned short* __restrict__ qr, unsigned short* __restrict__ kr,
                 float* __restrict__ koutf,
                 float* __restrict__ voutf, unsigned short* __restrict__ vt,
                 float* __restrict__ outf, const int* __restrict__ sp)
{
  const int tid  = threadIdx.x;
  const int lane = tid & 63;
  const int w    = tid >> 6;
  const int wr   = w >> 1, wc = w & 1;
  const int m0   = blockIdx.x * 128;
  const int n0   = blockIdx.y * 128;

  __shared__ unsigned short Alds[128 * 64];   // linear: row stride 128B
  __shared__ unsigned short Blds[128 * 64];

  f32x4 acc[4][4] = {};

  const unsigned short* Abase = A + (size_t)m0 * 2048;
  const unsigned short* Bbase = B + (size_t)n0 * 2048;
  const int rr = lane >> 3;          // 0..7
  const int cc = (lane & 7) * 8;     // element offset within 64-col chunk

  for (int k0 = 0; k0 < 2048; k0 += 64){
    __syncthreads();
    #pragma unroll
    for (int q = 0; q < 4; q++){
      int row = q*32 + w*8 + rr;
      __builtin_amdgcn_global_load_lds(
        (const __attribute__((address_space(1))) void*)(Abase + (size_t)row*2048 + k0 + cc),
        (__attribute__((address_space(3))) void*)((char*)Alds + q*4096 + w*1024),
        16, 0, 0);
      __builtin_amdgcn_global_load_lds(
        (const __attribute__((address_space(1))) void*)(Bbase + (size_t)row*2048 + k0 + cc),
        (__attribute__((address_space(3))) void*)((char*)Blds + q*4096 + w*1024),
        16, 0, 0);
    }
    __syncthreads();
    #pragma unroll
    for (int ks = 0; ks < 2; ks++){
      s16x8 af[4], bfr[4];
      const int kb = ks*64 + ((lane >> 4) << 4);   // byte offset within row
      #pragma unroll
      for (int i = 0; i < 4; i++){
        int r = wr*64 + i*16 + (lane & 15);
        af[i] = *(const s16x8*)((const char*)Alds + r*128 + kb);
      }
      #pragma unroll
      for (int j = 0; j < 4; j++){
        int r = wc*64 + j*16 + (lane & 15);
        bfr[j] = *(const s16x8*)((const char*)Blds + r*128 + kb);
      }
      #pragma unroll
      for (int i = 0; i < 4; i++)
        #pragma unroll
        for (int j = 0; j < 4; j++)
          acc[i][j] = mfma16(af[i], bfr[j], acc[i][j]);
    }
  }

  // ---- epilogue: C/D layout col=lane&15, row=(lane>>4)*4+reg ----
  const int col = lane & 15;
  const int rq  = (lane >> 4) << 2;

  if (MODE == 1){
    #pragma unroll
    for (int i = 0; i < 4; i++)
      #pragma unroll
      for (int j = 0; j < 4; j++)
        #pragma unroll
        for (int r = 0; r < 4; r++)
          outf[(size_t)(m0 + wr*64 + i*16 + rq + r) * DM + n0 + wc*64 + j*16 + col]
            = acc[i][j][r];
    return;
  }

  const int b = m0 >> 11;
  if (n0 < 4096){
    // ---- RoPE-fused Q/K epilogue ----
    const bool isK = (n0 >= 2048);
    unsigned short* dst = isK ? kr : qr;
    const int odd = lane & 1;
    const int sp0 = sp[0];
    const int nb  = n0 - (isK ? 2048 : 0);
    float fj[4];
    #pragma unroll
    for (int j = 0; j < 4; j++){
      int nn = nb + wc*64 + j*16 + col;
      fj[j] = exp2f(-(float)(nn >> 1) * (13.287712379549449f / 1024.0f));
    }
    #pragma unroll
    for (int i = 0; i < 4; i++){
      #pragma unroll
      for (int r = 0; r < 4; r++){
        int m = m0 + wr*64 + i*16 + rq + r;
        int s = m & 2047;
        float pos = (float)(sp0 + s);
        #pragma unroll
        for (int j = 0; j < 4; j++){
          float v  = acc[i][j][r];
          float vx = __shfl_xor(v, 1);
          float sn, cs;
          __sincosf(pos * fj[j], &sn, &cs);
          float x1 = odd ? vx : v;
          float x2 = odd ? v  : vx;
          float ov = odd ? (x1*sn + x2*cs) : (x1*cs - x2*sn);
          int nn = nb + wc*64 + j*16 + col;
          int c  = (nn >> 1) + (odd ? 1024 : 0);
          size_t adr = ((size_t)(b*NH + (c >> 7)) * SEQ + s) * HD + (c & 127);
          dst[adr] = f2b(ov);
          if (isK) koutf[adr] = ov;
        }
      }
    }
  } else {
    // ---- V epilogue: vout f32 (B,H,S,hd) + vt bf16 (B,H,hd,S) ----
    const int s_b = m0 & 2047;
    #pragma unroll
    for (int i = 0; i < 4; i++){
      int sb = s_b + wr*64 + i*16 + rq;
      #pragma unroll
      for (int j = 0; j < 4; j++){
        int d = (n0 - 4096) + wc*64 + j*16 + col;
        int h = d >> 7, dd = d & 127;
        size_t vbase = ((size_t)(b*NH + h) * SEQ + sb) * HD + dd;
        #pragma unroll
        for (int r = 0; r < 4; r++)
          voutf[vbase + (size_t)r * HD] = acc[i][j][r];
        ushort4 pk;
        pk.x = f2b(acc[i][j][0]); pk.y = f2b(acc[i][j][1]);
        pk.z = f2b(acc[i][j][2]); pk.w = f2b(acc[i][j][3]);
        *(ushort4*)(vt + ((size_t)(b*NH + h) * HD + dd) * SEQ + sb) = pk;
      }
    }
  }
}

// ---------------------------------------------------------------------------
// Causal flash attention, v3: block = 4 waves x 16 q-rows, KVBLK=32.
// Perfect load balance: block `pair` handles q-tiles {pair, 31-pair}
// sequentially (68 KV-tiles each, uniform). LDS 23KB: K 32x256B (XOR swz),
// V^T 128 rows @ 80B pitch, P per-wave 16 rows @ 80B pitch (no conflicts).
// Row-sum via ones-MFMA; defer-max rescale (THR=8).
// ---------------------------------------------------------------------------
__global__ __launch_bounds__(256)
void attn_kernel(const unsigned short* __restrict__ qr,
                 const unsigned short* __restrict__ kr,
                 const unsigned short* __restrict__ vt,
                 unsigned short* __restrict__ attnout)
{
  const int pair = blockIdx.x;          // 0..15
  const int bh   = blockIdx.y;          // 0..63
  const int tid  = threadIdx.x;
  const int lane = tid & 63;
  const int w    = tid >> 6;

  __shared__ __align__(16) char Klds[32 * 256];   // 8KB
  __shared__ __align__(16) char Vlds[128 * 80];   // 10KB
  __shared__ __align__(16) char Plds[4][16 * 80]; // 5KB

  const int l15 = lane & 15;
  const int lhi = lane >> 4;            // 0..3
  const int rq  = lhi << 2;
  char* pw = &Plds[w][0];

  s16x8 ones;
  #pragma unroll
  for (int i = 0; i < 8; i++) ones[i] = (short)0x3F80;  // bf16 1.0

  const int b = bh >> 4, h = bh & 15;

  for (int ph = 0; ph < 2; ph++){
    const int qtile = ph ? (31 - pair) : pair;
    const int q0w = qtile*64 + w*16;

    // Q fragments: row q0w + l15, k chunk c*32 + lhi*8
    s16x8 qf[4];
    const unsigned short* qbase = qr + ((size_t)bh*SEQ + q0w + l15) * HD + lhi*8;
    #pragma unroll
    for (int c = 0; c < 4; c++) qf[c] = *(const s16x8*)(qbase + c*32);

    f32x4 o[8] = {};
    f32x4 osum = {};
    float mrow[4] = {-1e30f,-1e30f,-1e30f,-1e30f};

    const int ntiles = 2*qtile + 2;
    for (int t = 0; t < ntiles; t++){
      const int kv0 = t * 32;
      __syncthreads();
      { // stage K tile (32 x 128 bf16, rows 256B, XOR swz (r&15)<<4)
        int r = tid >> 3, q8 = tid & 7;
        const unsigned short* src = kr + ((size_t)bh*SEQ + kv0 + r) * HD + q8*16;
        int sw = (r & 15) << 4;
        char* drow = Klds + r*256;
        *(s16x8*)(drow + (( q8*32      ) ^ sw)) = *(const s16x8*)(src);
        *(s16x8*)(drow + (( q8*32 + 16 ) ^ sw)) = *(const s16x8*)(src + 8);
      }
      { // stage V^T tile (128 d-rows x 32 kv, 80B pitch)
        int r = tid >> 1, hb = tid & 1;
        const unsigned short* src = vt + ((size_t)bh*HD + r) * SEQ + kv0 + hb*16;
        char* drow = Vlds + r*80 + hb*32;
        *(s16x8*)(drow)      = *(const s16x8*)(src);
        *(s16x8*)(drow + 16) = *(const s16x8*)(src + 8);
      }
      __syncthreads();

      // ---- S = Q K^T (16 q x 32 kv as two 16x16 tiles) ----
      f32x4 st[2];
      st[0] = (f32x4){0.f,0.f,0.f,0.f};
      st[1] = (f32x4){0.f,0.f,0.f,0.f};
      #pragma unroll
      for (int j = 0; j < 2; j++){
        int krw = j*16 + l15;
        int sw  = (krw & 15) << 4;
        #pragma unroll
        for (int c = 0; c < 4; c++){
          s16x8 kf = *(const s16x8*)(Klds + krw*256 + ((c*64 + lhi*16) ^ sw));
          st[j] = mfma16(qf[c], kf, st[j]);
        }
      }

      // ---- mask + scale ----
      const float sc = 0.08838834764831845f;  // 1/sqrt(128)
      #pragma unroll
      for (int j = 0; j < 2; j++)
        #pragma unroll
        for (int r = 0; r < 4; r++){
          int qrow = q0w + rq + r;
          int kvc  = kv0 + j*16 + l15;
          st[j][r] = (kvc > qrow) ? -1e30f : st[j][r] * sc;
        }

      // ---- row max (16-lane shfl reduce) + defer-max ----
      float mt[4];
      #pragma unroll
      for (int r = 0; r < 4; r++) mt[r] = fmaxf(st[0][r], st[1][r]);
      #pragma unroll
      for (int mk = 1; mk < 16; mk <<= 1)
        #pragma unroll
        for (int r = 0; r < 4; r++) mt[r] = fmaxf(mt[r], __shfl_xor(mt[r], mk));

      int ok = 1;
      #pragma unroll
      for (int r = 0; r < 4; r++) ok &= (mt[r] <= mrow[r] + 8.0f) ? 1 : 0;
      if (!__all(ok)){
        float al[4];
        #pragma unroll
        for (int r = 0; r < 4; r++){
          float mn = fmaxf(mrow[r], mt[r]);
          al[r] = __expf(mrow[r] - mn);
          mrow[r] = mn;
        }
        #pragma unroll
        for (int c = 0; c < 8; c++)
          #pragma unroll
          for (int r = 0; r < 4; r++) o[c][r] *= al[r];
        #pragma unroll
        for (int r = 0; r < 4; r++) osum[r] *= al[r];
      }

      // ---- P = exp(S - m), write to per-wave LDS (80B pitch rows) ----
      #pragma unroll
      for (int r = 0; r < 4; r++){
        char* prb = pw + (rq + r)*80;
        #pragma unroll
        for (int j = 0; j < 2; j++){
          float p = __expf(st[j][r] - mrow[r]);
          *(unsigned short*)(prb + (j*16 + l15)*2) = f2b(p);
        }
      }

      asm volatile("s_waitcnt lgkmcnt(0)" ::: "memory");

      // ---- O += P V ; rowsum via ones-MFMA ----
      s16x8 pa = *(const s16x8*)(pw + l15*80 + lhi*16);
      #pragma unroll
      for (int c = 0; c < 8; c++){
        int d = c*16 + l15;
        s16x8 vf = *(const s16x8*)(Vlds + d*80 + lhi*16);
        o[c] = mfma16(pa, vf, o[c]);
      }
      osum = mfma16(pa, ones, osum);
    }

    // ---- epilogue -> attn_out (B,S,D) bf16 ----
    #pragma unroll
    for (int r = 0; r < 4; r++){
      float inv = 1.0f / osum[r];
      int s2 = q0w + rq + r;
      size_t base = ((size_t)(b*SEQ + s2)) * DM + h*HD;
      #pragma unroll
      for (int c = 0; c < 8; c++)
        attnout[base + c*16 + l15] = f2b(o[c][r] * inv);
    }
  }
}

// ---------------------------------------------------------------------------
extern "C" void kernel_launch(void* const* d_in, const int* in_sizes, int n_in,
                              void* d_out, int out_size, void* d_ws, size_t ws_size,
                              hipStream_t stream)
{
  const float* x  = (const float*)d_in[0];
  const float* wq = (const float*)d_in[1];
  const float* wk = (const float*)d_in[2];
  const float* wv = (const float*)d_in[3];
  const float* wo = (const float*)d_in[4];
  const int*   sp = (const int*)d_in[5];

  float* out  = (float*)d_out;            // (B,S,D) f32
  float* kout = out + 16777216;           // (B,H,S,hd) f32
  float* vout = out + 33554432;           // (B,H,S,hd) f32

  char* ws = (char*)d_ws;
  unsigned short* xb      = (unsigned short*)ws;                  // 8192x2048 bf16 (33.55MB)
  unsigned short* wfused  = (unsigned short*)(ws + 33554432);     // 6144x2048 bf16 (25.17MB)
  unsigned short* wob     = (unsigned short*)(ws + 58720256);     // 2048x2048 bf16 (8.39MB)
  unsigned short* qr      = (unsigned short*)(ws + 67108864);     // (B,H,S,hd) bf16
  unsigned short* kr      = (unsigned short*)(ws + 100663296);    // (B,H,S,hd) bf16
  unsigned short* vt      = (unsigned short*)(ws + 134217728);    // (B,H,hd,S) bf16
  unsigned short* attnout = (unsigned short*)ws;                  // alias xb (dead after GEMM1)

  // 1) f32 -> bf16 conversion of activations + weights
  convert_kernel<<<16384, 256, 0, stream>>>(x, wq, wk, wv, wo, xb, wfused, wob);
  // 2) fused QKV GEMM with RoPE epilogue
  gemm_kernel<0><<<dim3(64, 48), 256, 0, stream>>>(xb, wfused, qr, kr, kout,
                                                   vout, vt, nullptr, sp);
  // 3) causal flash attention (paired q-tiles, uniform load)
  attn_kernel<<<dim3(16, 64), 256, 0, stream>>>(qr, kr, vt, attnout);
  // 4) output GEMM
  gemm_kernel<1><<<dim3(64, 16), 256, 0, stream>>>(attnout, wob, nullptr, nullptr,
                                                   nullptr, nullptr, nullptr, out, nullptr);
}

// Round 6
// 637.630 us; speedup vs baseline: 1.4939x; 1.0645x over previous
//
#include <hip/hip_runtime.h>
#include <hip/hip_bf16.h>

typedef __attribute__((ext_vector_type(4))) float f32x4;
typedef __attribute__((ext_vector_type(8))) short s16x8;

#define SEQ 2048
#define DM  2048
#define NH  16
#define HD  128

__device__ __forceinline__ unsigned short f2b(float f){
  unsigned int u = __builtin_bit_cast(unsigned int, f);
  u += 0x7fffu + ((u >> 16) & 1u);
  return (unsigned short)(u >> 16);
}
__device__ __forceinline__ float b2f(unsigned short h){
  unsigned int u = ((unsigned int)h) << 16;
  return __builtin_bit_cast(float, u);
}
__device__ __forceinline__ f32x4 mfma16(s16x8 a, s16x8 b, f32x4 c){
  return __builtin_amdgcn_mfma_f32_16x16x32_bf16(a, b, c, 0, 0, 0);
}

// ---------------------------------------------------------------------------
// One-shot f32 -> bf16 conversion: x -> xb, [wq|wk|wv] -> wfused, wo -> wob.
// ---------------------------------------------------------------------------
__global__ __launch_bounds__(256)
void convert_kernel(const float* __restrict__ x,  const float* __restrict__ wq,
                    const float* __restrict__ wk, const float* __restrict__ wv,
                    const float* __restrict__ wo,
                    unsigned short* __restrict__ xb,
                    unsigned short* __restrict__ wfused,
                    unsigned short* __restrict__ wob)
{
  size_t e = ((size_t)blockIdx.x * 256 + threadIdx.x) * 8;
  const float* src; unsigned short* dst;
  if (e < 16777216){ src = x + e; dst = xb + e; }
  else if (e < 29360128){
    size_t o = e - 16777216;
    int sel = (int)(o >> 22);
    const float* w = sel == 0 ? wq : (sel == 1 ? wk : wv);
    src = w + (o & 4194303); dst = wfused + o;
  } else {
    size_t o = e - 29360128;
    src = wo + o; dst = wob + o;
  }
  float4 a = ((const float4*)src)[0];
  float4 b = ((const float4*)src)[1];
  s16x8 v;
  v[0]=(short)f2b(a.x); v[1]=(short)f2b(a.y); v[2]=(short)f2b(a.z); v[3]=(short)f2b(a.w);
  v[4]=(short)f2b(b.x); v[5]=(short)f2b(b.y); v[6]=(short)f2b(b.z); v[7]=(short)f2b(b.w);
  *(s16x8*)dst = v;
}

// ---------------------------------------------------------------------------
// 8-phase 256x256 GEMM, BK=64, 8 waves (2Mx4N), 128KB dbuf LDS.
// Half-tiles split along K (256 rows x 32 cols, 64B rows). Involutive XOR
// swizzle: off ^= ((row>>1)&3)<<4 applied on pre-swizzled global source and
// swizzled ds_read. Counted vmcnt(4), raw s_barrier, setprio around MFMA.
// MODE 0: A=xb (M=8192), B=wfused (N=6144). nb 0-7 Q (RoPE->qr), 8-15 K
//         (RoPE->kr + f32 koutf), 16-23 V (f32 voutf + bf16 vt transposed).
//         RoPE via block-local LDS angle tables (angle addition).
// MODE 1: A=attnout, B=wob -> outf f32 (N=2048).
// ---------------------------------------------------------------------------
template<int MODE>
__global__ __launch_bounds__(512, 2)
void gemm8(const unsigned short* __restrict__ A,
           const unsigned short* __restrict__ B,
           unsigned short* __restrict__ qr, unsigned short* __restrict__ kr,
           float* __restrict__ koutf,
           float* __restrict__ voutf, unsigned short* __restrict__ vt,
           float* __restrict__ outf, const int* __restrict__ sp)
{
  extern __shared__ char lds[];
  const int tid  = threadIdx.x;
  const int lane = tid & 63;
  const int w    = tid >> 6;           // 0..7
  const int wr   = w >> 2;             // 0..1  (M half)
  const int wc   = w & 3;              // 0..3  (N quarter)
  const int l15  = lane & 15;
  const int lhi  = lane >> 4;          // 0..3
  const int rq   = lhi << 2;

  // XCD-aware bijective swizzle (nwg % 8 == 0 in both modes)
  const int NBN = (MODE == 0) ? 24 : 8;
  const int CPX = (MODE == 0) ? 96 : 32;
  int bid = blockIdx.x;
  int swz = (bid & 7) * CPX + (bid >> 3);
  const int mb = swz / NBN, nb = swz % NBN;
  const int m0 = mb * 256, n0 = nb * 256;

  const int sp0 = (MODE == 0) ? sp[0] : 0;

  const unsigned short* Abase = A + (size_t)m0 * 2048;
  const unsigned short* Bbase = B + (size_t)n0 * 2048;

  f32x4 accL[4][4] = {};   // M-frags 0-3
  f32x4 accH[4][4] = {};   // M-frags 4-7
  s16x8 af[4], bf[4];

  // ---- stage one half-tile (2 x global_load_lds, pre-swizzled source) ----
  auto STAGE = [&](const unsigned short* gbase, int ldsoff, int t, int ks){
    #pragma unroll
    for (int r2 = 0; r2 < 2; r2++){
      int p  = r2*8192 + w*1024 + (lane << 4);     // physical LDS offset
      int lo = p ^ (((p >> 7) & 3) << 4);          // logical (involution)
      int row = lo >> 6, colB = lo & 63;
      __builtin_amdgcn_global_load_lds(
        (const __attribute__((address_space(1))) void*)
          (gbase + (size_t)row*2048 + t*64 + ks*32 + (colB >> 1)),
        (__attribute__((address_space(3))) void*)(lds + ldsoff + r2*8192 + w*1024),
        16, 0, 0);
    }
  };
  auto SA = [&](int t, int ks){ STAGE(Abase, (t&1)*65536 +         ks*16384, t, ks); };
  auto SB = [&](int t, int ks){ STAGE(Bbase, (t&1)*65536 + 32768 + ks*16384, t, ks); };

  auto LDA4 = [&](int slot, int ks, int i0){
    const char* base = lds + slot*65536 + ks*16384;
    #pragma unroll
    for (int i = 0; i < 4; i++){
      int row = wr*128 + (i0 + i)*16 + l15;
      int off = row*64 + lhi*16;
      af[i] = *(const s16x8*)(base + (off ^ (((row >> 1) & 3) << 4)));
    }
  };
  auto LDB4 = [&](int slot, int ks){
    const char* base = lds + slot*65536 + 32768 + ks*16384;
    #pragma unroll
    for (int j = 0; j < 4; j++){
      int row = wc*64 + j*16 + l15;
      int off = row*64 + lhi*16;
      bf[j] = *(const s16x8*)(base + (off ^ (((row >> 1) & 3) << 4)));
    }
  };
  auto MM = [&](f32x4 (&ac)[4][4]){
    __builtin_amdgcn_s_setprio(1);
    #pragma unroll
    for (int i = 0; i < 4; i++)
      #pragma unroll
      for (int j = 0; j < 4; j++)
        ac[i][j] = mfma16(af[i], bf[j], ac[i][j]);
    __builtin_amdgcn_s_setprio(0);
  };

  // ---- prologue: stage tile 0 fully, wait first K-half ----
  SA(0,0); SB(0,0); SA(0,1); SB(0,1);
  asm volatile("s_waitcnt vmcnt(4)" ::: "memory");
  __builtin_amdgcn_s_barrier();

  // ---- main loop: tiles 0..30, tile 31 peeled ----
  #pragma unroll 2
  for (int t = 0; t < 31; t++){
    const int cs = t & 1;
    // P1: ks0, M 0-3
    LDB4(cs, 0); LDA4(cs, 0, 0);
    SA(t+1, 0);
    __builtin_amdgcn_s_barrier();
    MM(accL);
    __builtin_amdgcn_s_barrier();
    // P2: ks0, M 4-7
    LDA4(cs, 0, 4);
    SB(t+1, 0);
    __builtin_amdgcn_s_barrier();
    MM(accH);
    asm volatile("s_waitcnt vmcnt(4)" ::: "memory");  // Aks1(t),Bks1(t) landed
    __builtin_amdgcn_s_barrier();
    // P3: ks1, M 0-3
    LDB4(cs, 1); LDA4(cs, 1, 0);
    SA(t+1, 1);
    __builtin_amdgcn_s_barrier();
    MM(accL);
    __builtin_amdgcn_s_barrier();
    // P4: ks1, M 4-7
    LDA4(cs, 1, 4);
    SB(t+1, 1);
    __builtin_amdgcn_s_barrier();
    MM(accH);
    asm volatile("s_waitcnt vmcnt(4)" ::: "memory");  // ks0(t+1) landed
    __builtin_amdgcn_s_barrier();
  }
  { // tail tile 31 (slot 1), no staging
    LDB4(1, 0); LDA4(1, 0, 0);
    __builtin_amdgcn_s_barrier();
    MM(accL);
    __builtin_amdgcn_s_barrier();
    LDA4(1, 0, 4);
    __builtin_amdgcn_s_barrier();
    MM(accH);
    asm volatile("s_waitcnt vmcnt(0)" ::: "memory");
    __builtin_amdgcn_s_barrier();
    LDB4(1, 1); LDA4(1, 1, 0);
    __builtin_amdgcn_s_barrier();
    MM(accL);
    __builtin_amdgcn_s_barrier();
    LDA4(1, 1, 4);
    __builtin_amdgcn_s_barrier();
    MM(accH);
  }

  // ======================= epilogues =======================
  if (MODE == 1){
    #pragma unroll
    for (int h2 = 0; h2 < 2; h2++){
      f32x4 (&ac)[4][4] = h2 ? accH : accL;
      int ibase = h2 * 4;
      #pragma unroll
      for (int i = 0; i < 4; i++)
        #pragma unroll
        for (int r = 0; r < 4; r++){
          int m = m0 + wr*128 + (ibase+i)*16 + rq + r;
          #pragma unroll
          for (int j = 0; j < 4; j++)
            outf[(size_t)m*DM + n0 + wc*64 + j*16 + l15] = ac[i][j][r];
        }
    }
    return;
  }

  const int b  = m0 >> 11;
  const int s0 = m0 & 2047;

  if (nb < 16){
    // ---- RoPE Q/K epilogue with block-local LDS angle tables ----
    const bool isK = (nb >= 8);
    unsigned short* dqk = isK ? kr : qr;
    const int fbase = (nb & 7) * 128;
    const int odd = lane & 1;

    __syncthreads();   // all K-loop LDS reads done; reuse LDS for tables
    float2* T2 = (float2*)lds;             // [32 s_lo][128 f]
    float2* T1 = (float2*)(lds + 32768);   // [ 8 s_hi][128 f]
    for (int idx = tid; idx < 5120; idx += 512){
      int fl = idx & 127;
      float th = exp2f(-(float)(fbase + fl) * (13.287712379549449f / 1024.0f));
      float sn, cn;
      if (idx < 4096){
        __sincosf((float)(idx >> 7) * th, &sn, &cn);
        T2[idx] = make_float2(cn, sn);
      } else {
        int sh = (idx - 4096) >> 7;
        __sincosf((float)(sp0 + s0 + sh*32) * th, &sn, &cn);
        T1[idx - 4096] = make_float2(cn, sn);
      }
    }
    __syncthreads();

    #pragma unroll
    for (int h2 = 0; h2 < 2; h2++){
      f32x4 (&ac)[4][4] = h2 ? accH : accL;
      int ibase = h2 * 4;
      #pragma unroll
      for (int i = 0; i < 4; i++){
        #pragma unroll
        for (int r = 0; r < 4; r++){
          int srow = wr*128 + (ibase+i)*16 + rq + r;
          int s  = s0 + srow;
          int sh = srow >> 5, sl = srow & 31;
          #pragma unroll
          for (int j = 0; j < 4; j++){
            float v  = ac[i][j][r];
            float vx = __shfl_xor(v, 1);
            int nn_loc = wc*64 + j*16 + l15;
            int fl = nn_loc >> 1;
            float2 a1 = T1[sh*128 + fl];
            float2 a2 = T2[sl*128 + fl];
            float cn = a1.x*a2.x - a1.y*a2.y;
            float sn = a1.y*a2.x + a1.x*a2.y;
            float x1 = odd ? vx : v;
            float x2 = odd ? v  : vx;
            float ov = odd ? (x1*sn + x2*cn) : (x1*cn - x2*sn);
            int c = fbase + fl + (odd ? 1024 : 0);
            size_t adr = ((size_t)(b*NH + (c >> 7))*SEQ + s)*HD + (c & 127);
            dqk[adr] = f2b(ov);
            if (isK) koutf[adr] = ov;
          }
        }
      }
    }
  } else {
    // ---- V epilogue: vout f32 (B,H,S,hd) + vt bf16 (B,H,hd,S) ----
    #pragma unroll
    for (int h2 = 0; h2 < 2; h2++){
      f32x4 (&ac)[4][4] = h2 ? accH : accL;
      int ibase = h2 * 4;
      #pragma unroll
      for (int i = 0; i < 4; i++){
        int sb = s0 + wr*128 + (ibase+i)*16 + rq;
        #pragma unroll
        for (int j = 0; j < 4; j++){
          int d = (nb - 16)*256 + wc*64 + j*16 + l15;
          int h = d >> 7, dd = d & 127;
          size_t vb = ((size_t)(b*NH + h)*SEQ + sb)*HD + dd;
          #pragma unroll
          for (int r = 0; r < 4; r++)
            voutf[vb + (size_t)r*HD] = ac[i][j][r];
          ushort4 pk;
          pk.x = f2b(ac[i][j][0]); pk.y = f2b(ac[i][j][1]);
          pk.z = f2b(ac[i][j][2]); pk.w = f2b(ac[i][j][3]);
          *(ushort4*)(vt + ((size_t)(b*NH + h)*HD + dd)*SEQ + sb) = pk;
        }
      }
    }
  }
}

// ---------------------------------------------------------------------------
// Causal flash attention (Round-5 version: paired q-tiles, 80B pitches,
// ones-MFMA rowsum, defer-max).
// ---------------------------------------------------------------------------
__global__ __launch_bounds__(256)
void attn_kernel(const unsigned short* __restrict__ qr,
                 const unsigned short* __restrict__ kr,
                 const unsigned short* __restrict__ vt,
                 unsigned short* __restrict__ attnout)
{
  const int pair = blockIdx.x;          // 0..15
  const int bh   = blockIdx.y;          // 0..63
  const int tid  = threadIdx.x;
  const int lane = tid & 63;
  const int w    = tid >> 6;

  __shared__ __align__(16) char Klds[32 * 256];   // 8KB
  __shared__ __align__(16) char Vlds[128 * 80];   // 10KB
  __shared__ __align__(16) char Plds[4][16 * 80]; // 5KB

  const int l15 = lane & 15;
  const int lhi = lane >> 4;
  const int rq  = lhi << 2;
  char* pw = &Plds[w][0];

  s16x8 ones;
  #pragma unroll
  for (int i = 0; i < 8; i++) ones[i] = (short)0x3F80;

  const int b = bh >> 4, h = bh & 15;

  for (int ph = 0; ph < 2; ph++){
    const int qtile = ph ? (31 - pair) : pair;
    const int q0w = qtile*64 + w*16;

    s16x8 qf[4];
    const unsigned short* qbase = qr + ((size_t)bh*SEQ + q0w + l15) * HD + lhi*8;
    #pragma unroll
    for (int c = 0; c < 4; c++) qf[c] = *(const s16x8*)(qbase + c*32);

    f32x4 o[8] = {};
    f32x4 osum = {};
    float mrow[4] = {-1e30f,-1e30f,-1e30f,-1e30f};

    const int ntiles = 2*qtile + 2;
    for (int t = 0; t < ntiles; t++){
      const int kv0 = t * 32;
      __syncthreads();
      { // stage K tile (32 x 128 bf16, rows 256B, XOR swz (r&15)<<4)
        int r = tid >> 3, q8 = tid & 7;
        const unsigned short* src = kr + ((size_t)bh*SEQ + kv0 + r) * HD + q8*16;
        int sw = (r & 15) << 4;
        char* drow = Klds + r*256;
        *(s16x8*)(drow + (( q8*32      ) ^ sw)) = *(const s16x8*)(src);
        *(s16x8*)(drow + (( q8*32 + 16 ) ^ sw)) = *(const s16x8*)(src + 8);
      }
      { // stage V^T tile (128 d-rows x 32 kv, 80B pitch)
        int r = tid >> 1, hb = tid & 1;
        const unsigned short* src = vt + ((size_t)bh*HD + r) * SEQ + kv0 + hb*16;
        char* drow = Vlds + r*80 + hb*32;
        *(s16x8*)(drow)      = *(const s16x8*)(src);
        *(s16x8*)(drow + 16) = *(const s16x8*)(src + 8);
      }
      __syncthreads();

      f32x4 st[2];
      st[0] = (f32x4){0.f,0.f,0.f,0.f};
      st[1] = (f32x4){0.f,0.f,0.f,0.f};
      #pragma unroll
      for (int j = 0; j < 2; j++){
        int krw = j*16 + l15;
        int sw  = (krw & 15) << 4;
        #pragma unroll
        for (int c = 0; c < 4; c++){
          s16x8 kf = *(const s16x8*)(Klds + krw*256 + ((c*64 + lhi*16) ^ sw));
          st[j] = mfma16(qf[c], kf, st[j]);
        }
      }

      const float sc = 0.08838834764831845f;
      #pragma unroll
      for (int j = 0; j < 2; j++)
        #pragma unroll
        for (int r = 0; r < 4; r++){
          int qrow = q0w + rq + r;
          int kvc  = kv0 + j*16 + l15;
          st[j][r] = (kvc > qrow) ? -1e30f : st[j][r] * sc;
        }

      float mt[4];
      #pragma unroll
      for (int r = 0; r < 4; r++) mt[r] = fmaxf(st[0][r], st[1][r]);
      #pragma unroll
      for (int mk = 1; mk < 16; mk <<= 1)
        #pragma unroll
        for (int r = 0; r < 4; r++) mt[r] = fmaxf(mt[r], __shfl_xor(mt[r], mk));

      int ok = 1;
      #pragma unroll
      for (int r = 0; r < 4; r++) ok &= (mt[r] <= mrow[r] + 8.0f) ? 1 : 0;
      if (!__all(ok)){
        float al[4];
        #pragma unroll
        for (int r = 0; r < 4; r++){
          float mn = fmaxf(mrow[r], mt[r]);
          al[r] = __expf(mrow[r] - mn);
          mrow[r] = mn;
        }
        #pragma unroll
        for (int c = 0; c < 8; c++)
          #pragma unroll
          for (int r = 0; r < 4; r++) o[c][r] *= al[r];
        #pragma unroll
        for (int r = 0; r < 4; r++) osum[r] *= al[r];
      }

      #pragma unroll
      for (int r = 0; r < 4; r++){
        char* prb = pw + (rq + r)*80;
        #pragma unroll
        for (int j = 0; j < 2; j++){
          float p = __expf(st[j][r] - mrow[r]);
          *(unsigned short*)(prb + (j*16 + l15)*2) = f2b(p);
        }
      }

      asm volatile("s_waitcnt lgkmcnt(0)" ::: "memory");

      s16x8 pa = *(const s16x8*)(pw + l15*80 + lhi*16);
      #pragma unroll
      for (int c = 0; c < 8; c++){
        int d = c*16 + l15;
        s16x8 vf = *(const s16x8*)(Vlds + d*80 + lhi*16);
        o[c] = mfma16(pa, vf, o[c]);
      }
      osum = mfma16(pa, ones, osum);
    }

    #pragma unroll
    for (int r = 0; r < 4; r++){
      float inv = 1.0f / osum[r];
      int s2 = q0w + rq + r;
      size_t base = ((size_t)(b*SEQ + s2)) * DM + h*HD;
      #pragma unroll
      for (int c = 0; c < 8; c++)
        attnout[base + c*16 + l15] = f2b(o[c][r] * inv);
    }
  }
}

// ---------------------------------------------------------------------------
extern "C" void kernel_launch(void* const* d_in, const int* in_sizes, int n_in,
                              void* d_out, int out_size, void* d_ws, size_t ws_size,
                              hipStream_t stream)
{
  const float* x  = (const float*)d_in[0];
  const float* wq = (const float*)d_in[1];
  const float* wk = (const float*)d_in[2];
  const float* wv = (const float*)d_in[3];
  const float* wo = (const float*)d_in[4];
  const int*   sp = (const int*)d_in[5];

  float* out  = (float*)d_out;            // (B,S,D) f32
  float* kout = out + 16777216;           // (B,H,S,hd) f32
  float* vout = out + 33554432;           // (B,H,S,hd) f32

  char* ws = (char*)d_ws;
  unsigned short* xb      = (unsigned short*)ws;                  // 8192x2048 bf16
  unsigned short* wfused  = (unsigned short*)(ws + 33554432);     // 6144x2048 bf16
  unsigned short* wob     = (unsigned short*)(ws + 58720256);     // 2048x2048 bf16
  unsigned short* qr      = (unsigned short*)(ws + 67108864);     // (B,H,S,hd) bf16
  unsigned short* kr      = (unsigned short*)(ws + 100663296);    // (B,H,S,hd) bf16
  unsigned short* vt      = (unsigned short*)(ws + 134217728);    // (B,H,hd,S) bf16
  unsigned short* attnout = (unsigned short*)ws;                  // alias xb

  hipFuncSetAttribute((const void*)gemm8<0>,
                      hipFuncAttributeMaxDynamicSharedMemorySize, 131072);
  hipFuncSetAttribute((const void*)gemm8<1>,
                      hipFuncAttributeMaxDynamicSharedMemorySize, 131072);

  // 1) f32 -> bf16 conversion
  convert_kernel<<<16384, 256, 0, stream>>>(x, wq, wk, wv, wo, xb, wfused, wob);
  // 2) fused QKV GEMM (8-phase 256^2) with RoPE/V epilogues
  gemm8<0><<<768, 512, 131072, stream>>>(xb, wfused, qr, kr, kout,
                                         vout, vt, nullptr, sp);
  // 3) causal flash attention
  attn_kernel<<<dim3(16, 64), 256, 0, stream>>>(qr, kr, vt, attnout);
  // 4) output GEMM (8-phase 256^2)
  gemm8<1><<<256, 512, 131072, stream>>>(attnout, wob, nullptr, nullptr,
                                         nullptr, nullptr, nullptr, out, nullptr);
}

// Round 7
// 599.882 us; speedup vs baseline: 1.5879x; 1.0629x over previous
//
#include <hip/hip_runtime.h>
#include <hip/hip_bf16.h>

typedef __attribute__((ext_vector_type(4))) float f32x4;
typedef __attribute__((ext_vector_type(8))) short s16x8;

#define SEQ 2048
#define DM  2048
#define NH  16
#define HD  128

__device__ __forceinline__ unsigned short f2b(float f){
  unsigned int u = __builtin_bit_cast(unsigned int, f);
  u += 0x7fffu + ((u >> 16) & 1u);
  return (unsigned short)(u >> 16);
}
__device__ __forceinline__ float b2f(unsigned short h){
  unsigned int u = ((unsigned int)h) << 16;
  return __builtin_bit_cast(float, u);
}
__device__ __forceinline__ f32x4 mfma16(s16x8 a, s16x8 b, f32x4 c){
  return __builtin_amdgcn_mfma_f32_16x16x32_bf16(a, b, c, 0, 0, 0);
}

// ---------------------------------------------------------------------------
// One-shot f32 -> bf16 conversion: x -> xb, [wq|wk|wv] -> wfused, wo -> wob.
// ---------------------------------------------------------------------------
__global__ __launch_bounds__(256)
void convert_kernel(const float* __restrict__ x,  const float* __restrict__ wq,
                    const float* __restrict__ wk, const float* __restrict__ wv,
                    const float* __restrict__ wo,
                    unsigned short* __restrict__ xb,
                    unsigned short* __restrict__ wfused,
                    unsigned short* __restrict__ wob)
{
  size_t e = ((size_t)blockIdx.x * 256 + threadIdx.x) * 8;
  const float* src; unsigned short* dst;
  if (e < 16777216){ src = x + e; dst = xb + e; }
  else if (e < 29360128){
    size_t o = e - 16777216;
    int sel = (int)(o >> 22);
    const float* w = sel == 0 ? wq : (sel == 1 ? wk : wv);
    src = w + (o & 4194303); dst = wfused + o;
  } else {
    size_t o = e - 29360128;
    src = wo + o; dst = wob + o;
  }
  float4 a = ((const float4*)src)[0];
  float4 b = ((const float4*)src)[1];
  s16x8 v;
  v[0]=(short)f2b(a.x); v[1]=(short)f2b(a.y); v[2]=(short)f2b(a.z); v[3]=(short)f2b(a.w);
  v[4]=(short)f2b(b.x); v[5]=(short)f2b(b.y); v[6]=(short)f2b(b.z); v[7]=(short)f2b(b.w);
  *(s16x8*)dst = v;
}

// ---------------------------------------------------------------------------
// 8-phase 256x256 GEMM, BK=64, 8 waves (2Mx4N), 128KB dbuf LDS.
// Half-tiles split along K (256 rows x 32 cols, 64B rows). Involutive XOR
// swizzle. Counted vmcnt(4), raw s_barrier, setprio around MFMA.
// L2 policy: XCD x owns a fixed 3-nb (MODE0) / 1-nb (MODE1) strip so its
// B-panels stay L2-resident for the whole kernel; A-panels stream with
// 3-consecutive-block reuse.
// ---------------------------------------------------------------------------
template<int MODE>
__global__ __launch_bounds__(512, 2)
void gemm8(const unsigned short* __restrict__ A,
           const unsigned short* __restrict__ B,
           unsigned short* __restrict__ qr, unsigned short* __restrict__ kr,
           float* __restrict__ koutf,
           float* __restrict__ voutf, unsigned short* __restrict__ vt,
           float* __restrict__ outf, const int* __restrict__ sp)
{
  extern __shared__ char lds[];
  const int tid  = threadIdx.x;
  const int lane = tid & 63;
  const int w    = tid >> 6;           // 0..7
  const int wr   = w >> 2;             // 0..1  (M half)
  const int wc   = w & 3;              // 0..3  (N quarter)
  const int l15  = lane & 15;
  const int lhi  = lane >> 4;          // 0..3
  const int rq   = lhi << 2;

  // XCD-resident B-strips: MODE0 nb = 3x + j%3 (B 3MB/XCD), MODE1 nb = x.
  int bid = blockIdx.x;
  int x8 = bid & 7, j = bid >> 3;
  int mb, nb;
  if (MODE == 0){ nb = 3*x8 + (j % 3); mb = j / 3; }
  else          { nb = x8;             mb = j; }
  const int m0 = mb * 256, n0 = nb * 256;

  const int sp0 = (MODE == 0) ? sp[0] : 0;

  const unsigned short* Abase = A + (size_t)m0 * 2048;
  const unsigned short* Bbase = B + (size_t)n0 * 2048;

  f32x4 accL[4][4] = {};   // M-frags 0-3
  f32x4 accH[4][4] = {};   // M-frags 4-7
  s16x8 af[4], bf[4];

  // ---- stage one half-tile (2 x global_load_lds, pre-swizzled source) ----
  auto STAGE = [&](const unsigned short* gbase, int ldsoff, int t, int ks){
    #pragma unroll
    for (int r2 = 0; r2 < 2; r2++){
      int p  = r2*8192 + w*1024 + (lane << 4);     // physical LDS offset
      int lo = p ^ (((p >> 7) & 3) << 4);          // logical (involution)
      int row = lo >> 6, colB = lo & 63;
      __builtin_amdgcn_global_load_lds(
        (const __attribute__((address_space(1))) void*)
          (gbase + (size_t)row*2048 + t*64 + ks*32 + (colB >> 1)),
        (__attribute__((address_space(3))) void*)(lds + ldsoff + r2*8192 + w*1024),
        16, 0, 0);
    }
  };
  auto SA = [&](int t, int ks){ STAGE(Abase, (t&1)*65536 +         ks*16384, t, ks); };
  auto SB = [&](int t, int ks){ STAGE(Bbase, (t&1)*65536 + 32768 + ks*16384, t, ks); };

  auto LDA4 = [&](int slot, int ks, int i0){
    const char* base = lds + slot*65536 + ks*16384;
    #pragma unroll
    for (int i = 0; i < 4; i++){
      int row = wr*128 + (i0 + i)*16 + l15;
      int off = row*64 + lhi*16;
      af[i] = *(const s16x8*)(base + (off ^ (((row >> 1) & 3) << 4)));
    }
  };
  auto LDB4 = [&](int slot, int ks){
    const char* base = lds + slot*65536 + 32768 + ks*16384;
    #pragma unroll
    for (int j2 = 0; j2 < 4; j2++){
      int row = wc*64 + j2*16 + l15;
      int off = row*64 + lhi*16;
      bf[j2] = *(const s16x8*)(base + (off ^ (((row >> 1) & 3) << 4)));
    }
  };
  auto MM = [&](f32x4 (&ac)[4][4]){
    __builtin_amdgcn_s_setprio(1);
    #pragma unroll
    for (int i = 0; i < 4; i++)
      #pragma unroll
      for (int j2 = 0; j2 < 4; j2++)
        ac[i][j2] = mfma16(af[i], bf[j2], ac[i][j2]);
    __builtin_amdgcn_s_setprio(0);
  };

  // ---- prologue: stage tile 0 fully, wait first K-half ----
  SA(0,0); SB(0,0); SA(0,1); SB(0,1);
  asm volatile("s_waitcnt vmcnt(4)" ::: "memory");
  __builtin_amdgcn_s_barrier();

  // ---- main loop: tiles 0..30, tile 31 peeled ----
  #pragma unroll 2
  for (int t = 0; t < 31; t++){
    const int cs = t & 1;
    // P1: ks0, M 0-3
    LDB4(cs, 0); LDA4(cs, 0, 0);
    SA(t+1, 0);
    __builtin_amdgcn_s_barrier();
    MM(accL);
    __builtin_amdgcn_s_barrier();
    // P2: ks0, M 4-7
    LDA4(cs, 0, 4);
    SB(t+1, 0);
    __builtin_amdgcn_s_barrier();
    MM(accH);
    asm volatile("s_waitcnt vmcnt(4)" ::: "memory");  // Aks1(t),Bks1(t) landed
    __builtin_amdgcn_s_barrier();
    // P3: ks1, M 0-3
    LDB4(cs, 1); LDA4(cs, 1, 0);
    SA(t+1, 1);
    __builtin_amdgcn_s_barrier();
    MM(accL);
    __builtin_amdgcn_s_barrier();
    // P4: ks1, M 4-7
    LDA4(cs, 1, 4);
    SB(t+1, 1);
    __builtin_amdgcn_s_barrier();
    MM(accH);
    asm volatile("s_waitcnt vmcnt(4)" ::: "memory");  // ks0(t+1) landed
    __builtin_amdgcn_s_barrier();
  }
  { // tail tile 31 (slot 1), no staging
    LDB4(1, 0); LDA4(1, 0, 0);
    __builtin_amdgcn_s_barrier();
    MM(accL);
    __builtin_amdgcn_s_barrier();
    LDA4(1, 0, 4);
    __builtin_amdgcn_s_barrier();
    MM(accH);
    asm volatile("s_waitcnt vmcnt(0)" ::: "memory");
    __builtin_amdgcn_s_barrier();
    LDB4(1, 1); LDA4(1, 1, 0);
    __builtin_amdgcn_s_barrier();
    MM(accL);
    __builtin_amdgcn_s_barrier();
    LDA4(1, 1, 4);
    __builtin_amdgcn_s_barrier();
    MM(accH);
  }

  // ======================= epilogues =======================
  if (MODE == 1){
    #pragma unroll
    for (int h2 = 0; h2 < 2; h2++){
      f32x4 (&ac)[4][4] = h2 ? accH : accL;
      int ibase = h2 * 4;
      #pragma unroll
      for (int i = 0; i < 4; i++)
        #pragma unroll
        for (int r = 0; r < 4; r++){
          int m = m0 + wr*128 + (ibase+i)*16 + rq + r;
          #pragma unroll
          for (int j2 = 0; j2 < 4; j2++)
            outf[(size_t)m*DM + n0 + wc*64 + j2*16 + l15] = ac[i][j2][r];
        }
    }
    return;
  }

  const int b  = m0 >> 11;
  const int s0 = m0 & 2047;

  if (nb < 16){
    // ---- RoPE Q/K epilogue with block-local LDS angle tables ----
    const bool isK = (nb >= 8);
    unsigned short* dqk = isK ? kr : qr;
    const int fbase = (nb & 7) * 128;
    const int odd = lane & 1;

    __syncthreads();   // all K-loop LDS reads done; reuse LDS for tables
    float2* T2 = (float2*)lds;             // [32 s_lo][128 f]
    float2* T1 = (float2*)(lds + 32768);   // [ 8 s_hi][128 f]
    for (int idx = tid; idx < 5120; idx += 512){
      int fl = idx & 127;
      float th = exp2f(-(float)(fbase + fl) * (13.287712379549449f / 1024.0f));
      float sn, cn;
      if (idx < 4096){
        __sincosf((float)(idx >> 7) * th, &sn, &cn);
        T2[idx] = make_float2(cn, sn);
      } else {
        int sh = (idx - 4096) >> 7;
        __sincosf((float)(sp0 + s0 + sh*32) * th, &sn, &cn);
        T1[idx - 4096] = make_float2(cn, sn);
      }
    }
    __syncthreads();

    #pragma unroll
    for (int h2 = 0; h2 < 2; h2++){
      f32x4 (&ac)[4][4] = h2 ? accH : accL;
      int ibase = h2 * 4;
      #pragma unroll
      for (int i = 0; i < 4; i++){
        #pragma unroll
        for (int r = 0; r < 4; r++){
          int srow = wr*128 + (ibase+i)*16 + rq + r;
          int s  = s0 + srow;
          int sh = srow >> 5, sl = srow & 31;
          #pragma unroll
          for (int j2 = 0; j2 < 4; j2++){
            float v  = ac[i][j2][r];
            float vx = __shfl_xor(v, 1);
            int nn_loc = wc*64 + j2*16 + l15;
            int fl = nn_loc >> 1;
            float2 a1 = T1[sh*128 + fl];
            float2 a2 = T2[sl*128 + fl];
            float cn = a1.x*a2.x - a1.y*a2.y;
            float sn = a1.y*a2.x + a1.x*a2.y;
            float x1 = odd ? vx : v;
            float x2 = odd ? v  : vx;
            float ov = odd ? (x1*sn + x2*cn) : (x1*cn - x2*sn);
            int c = fbase + fl + (odd ? 1024 : 0);
            size_t adr = ((size_t)(b*NH + (c >> 7))*SEQ + s)*HD + (c & 127);
            dqk[adr] = f2b(ov);
            if (isK) koutf[adr] = ov;
          }
        }
      }
    }
  } else {
    // ---- V epilogue: vout f32 (B,H,S,hd) + vt bf16 (B,H,hd,S) ----
    #pragma unroll
    for (int h2 = 0; h2 < 2; h2++){
      f32x4 (&ac)[4][4] = h2 ? accH : accL;
      int ibase = h2 * 4;
      #pragma unroll
      for (int i = 0; i < 4; i++){
        int sb = s0 + wr*128 + (ibase+i)*16 + rq;
        #pragma unroll
        for (int j2 = 0; j2 < 4; j2++){
          int d = (nb - 16)*256 + wc*64 + j2*16 + l15;
          int h = d >> 7, dd = d & 127;
          size_t vb = ((size_t)(b*NH + h)*SEQ + sb)*HD + dd;
          #pragma unroll
          for (int r = 0; r < 4; r++)
            voutf[vb + (size_t)r*HD] = ac[i][j2][r];
          ushort4 pk;
          pk.x = f2b(ac[i][j2][0]); pk.y = f2b(ac[i][j2][1]);
          pk.z = f2b(ac[i][j2][2]); pk.w = f2b(ac[i][j2][3]);
          *(ushort4*)(vt + ((size_t)(b*NH + h)*HD + dd)*SEQ + sb) = pk;
        }
      }
    }
  }
}

// ---------------------------------------------------------------------------
// Causal flash attention v4: 4 waves x 16 q-rows, KVBLK=64 (halved softmax /
// barrier overhead per KV element vs KVBLK=32). Paired q-tiles for uniform
// load. K 64x256B XOR-swz; V^T / P at 144B pitch (2-way max). Row-sum via
// ones-MFMA; defer-max (THR=8).
// ---------------------------------------------------------------------------
__global__ __launch_bounds__(256)
void attn_kernel(const unsigned short* __restrict__ qr,
                 const unsigned short* __restrict__ kr,
                 const unsigned short* __restrict__ vt,
                 unsigned short* __restrict__ attnout)
{
  const int pair = blockIdx.x;          // 0..15
  const int bh   = blockIdx.y;          // 0..63
  const int tid  = threadIdx.x;
  const int lane = tid & 63;
  const int w    = tid >> 6;

  __shared__ __align__(16) char Klds[64 * 256];    // 16KB
  __shared__ __align__(16) char Vlds[128 * 144];   // 18KB
  __shared__ __align__(16) char Plds[4][16 * 144]; // 9KB

  const int l15 = lane & 15;
  const int lhi = lane >> 4;
  const int rq  = lhi << 2;
  char* pw = &Plds[w][0];

  s16x8 ones;
  #pragma unroll
  for (int i = 0; i < 8; i++) ones[i] = (short)0x3F80;

  const int b = bh >> 4, h = bh & 15;

  for (int ph = 0; ph < 2; ph++){
    const int qtile = ph ? (31 - pair) : pair;
    const int q0w = qtile*64 + w*16;

    s16x8 qf[4];
    const unsigned short* qbase = qr + ((size_t)bh*SEQ + q0w + l15) * HD + lhi*8;
    #pragma unroll
    for (int c = 0; c < 4; c++) qf[c] = *(const s16x8*)(qbase + c*32);

    f32x4 o[8] = {};
    f32x4 osum = {};
    float mrow[4] = {-1e30f,-1e30f,-1e30f,-1e30f};

    const int ntiles = qtile + 1;
    for (int t = 0; t < ntiles; t++){
      const int kv0 = t * 64;
      __syncthreads();
      { // stage K tile (64 x 128 bf16, rows 256B, XOR swz (r&15)<<4)
        int r = tid >> 2, q4 = tid & 3;
        const unsigned short* src = kr + ((size_t)bh*SEQ + kv0 + r) * HD + q4*32;
        int sw = (r & 15) << 4;
        char* drow = Klds + r*256;
        #pragma unroll
        for (int k = 0; k < 4; k++)
          *(s16x8*)(drow + ((q4*64 + k*16) ^ sw)) = *(const s16x8*)(src + k*8);
      }
      { // stage V^T tile (128 d-rows x 64 kv, 144B pitch)
        int r = tid >> 1, h2 = tid & 1;
        const unsigned short* src = vt + ((size_t)bh*HD + r) * SEQ + kv0 + h2*32;
        char* drow = Vlds + r*144 + h2*64;
        #pragma unroll
        for (int k = 0; k < 4; k++)
          *(s16x8*)(drow + k*16) = *(const s16x8*)(src + k*8);
      }
      __syncthreads();

      // ---- S = Q K^T (16 q x 64 kv as four 16x16 tiles) ----
      f32x4 st[4];
      #pragma unroll
      for (int j = 0; j < 4; j++) st[j] = (f32x4){0.f,0.f,0.f,0.f};
      #pragma unroll
      for (int j = 0; j < 4; j++){
        int krw = j*16 + l15;
        int sw  = (krw & 15) << 4;
        #pragma unroll
        for (int c = 0; c < 4; c++){
          s16x8 kf = *(const s16x8*)(Klds + krw*256 + ((c*64 + lhi*16) ^ sw));
          st[j] = mfma16(qf[c], kf, st[j]);
        }
      }

      const float sc = 0.08838834764831845f;
      #pragma unroll
      for (int j = 0; j < 4; j++)
        #pragma unroll
        for (int r = 0; r < 4; r++){
          int qrow = q0w + rq + r;
          int kvc  = kv0 + j*16 + l15;
          st[j][r] = (kvc > qrow) ? -1e30f : st[j][r] * sc;
        }

      float mt[4];
      #pragma unroll
      for (int r = 0; r < 4; r++)
        mt[r] = fmaxf(fmaxf(st[0][r], st[1][r]), fmaxf(st[2][r], st[3][r]));
      #pragma unroll
      for (int mk = 1; mk < 16; mk <<= 1)
        #pragma unroll
        for (int r = 0; r < 4; r++) mt[r] = fmaxf(mt[r], __shfl_xor(mt[r], mk));

      int ok = 1;
      #pragma unroll
      for (int r = 0; r < 4; r++) ok &= (mt[r] <= mrow[r] + 8.0f) ? 1 : 0;
      if (!__all(ok)){
        float al[4];
        #pragma unroll
        for (int r = 0; r < 4; r++){
          float mn = fmaxf(mrow[r], mt[r]);
          al[r] = __expf(mrow[r] - mn);
          mrow[r] = mn;
        }
        #pragma unroll
        for (int c = 0; c < 8; c++)
          #pragma unroll
          for (int r = 0; r < 4; r++) o[c][r] *= al[r];
        #pragma unroll
        for (int r = 0; r < 4; r++) osum[r] *= al[r];
      }

      // ---- P = exp(S - m) -> per-wave LDS (144B pitch) ----
      #pragma unroll
      for (int r = 0; r < 4; r++){
        char* prb = pw + (rq + r)*144;
        #pragma unroll
        for (int j = 0; j < 4; j++){
          float p = __expf(st[j][r] - mrow[r]);
          *(unsigned short*)(prb + (j*16 + l15)*2) = f2b(p);
        }
      }

      asm volatile("s_waitcnt lgkmcnt(0)" ::: "memory");

      // ---- O += P V (two K=32 passes) ----
      #pragma unroll
      for (int ks = 0; ks < 2; ks++){
        s16x8 pa = *(const s16x8*)(pw + l15*144 + ks*64 + lhi*16);
        #pragma unroll
        for (int c = 0; c < 8; c++){
          int d = c*16 + l15;
          s16x8 vf = *(const s16x8*)(Vlds + d*144 + ks*64 + lhi*16);
          o[c] = mfma16(pa, vf, o[c]);
        }
        osum = mfma16(pa, ones, osum);
      }
    }

    #pragma unroll
    for (int r = 0; r < 4; r++){
      float inv = 1.0f / osum[r];
      int s2 = q0w + rq + r;
      size_t base = ((size_t)(b*SEQ + s2)) * DM + h*HD;
      #pragma unroll
      for (int c = 0; c < 8; c++)
        attnout[base + c*16 + l15] = f2b(o[c][r] * inv);
    }
  }
}

// ---------------------------------------------------------------------------
extern "C" void kernel_launch(void* const* d_in, const int* in_sizes, int n_in,
                              void* d_out, int out_size, void* d_ws, size_t ws_size,
                              hipStream_t stream)
{
  const float* x  = (const float*)d_in[0];
  const float* wq = (const float*)d_in[1];
  const float* wk = (const float*)d_in[2];
  const float* wv = (const float*)d_in[3];
  const float* wo = (const float*)d_in[4];
  const int*   sp = (const int*)d_in[5];

  float* out  = (float*)d_out;            // (B,S,D) f32
  float* kout = out + 16777216;           // (B,H,S,hd) f32
  float* vout = out + 33554432;           // (B,H,S,hd) f32

  char* ws = (char*)d_ws;
  unsigned short* xb      = (unsigned short*)ws;                  // 8192x2048 bf16
  unsigned short* wfused  = (unsigned short*)(ws + 33554432);     // 6144x2048 bf16
  unsigned short* wob     = (unsigned short*)(ws + 58720256);     // 2048x2048 bf16
  unsigned short* qr      = (unsigned short*)(ws + 67108864);     // (B,H,S,hd) bf16
  unsigned short* kr      = (unsigned short*)(ws + 100663296);    // (B,H,S,hd) bf16
  unsigned short* vt      = (unsigned short*)(ws + 134217728);    // (B,H,hd,S) bf16
  unsigned short* attnout = (unsigned short*)ws;                  // alias xb

  hipFuncSetAttribute((const void*)gemm8<0>,
                      hipFuncAttributeMaxDynamicSharedMemorySize, 131072);
  hipFuncSetAttribute((const void*)gemm8<1>,
                      hipFuncAttributeMaxDynamicSharedMemorySize, 131072);

  // 1) f32 -> bf16 conversion
  convert_kernel<<<16384, 256, 0, stream>>>(x, wq, wk, wv, wo, xb, wfused, wob);
  // 2) fused QKV GEMM (8-phase 256^2, XCD-resident B strips)
  gemm8<0><<<768, 512, 131072, stream>>>(xb, wfused, qr, kr, kout,
                                         vout, vt, nullptr, sp);
  // 3) causal flash attention (KVBLK=64, paired q-tiles)
  attn_kernel<<<dim3(16, 64), 256, 0, stream>>>(qr, kr, vt, attnout);
  // 4) output GEMM (8-phase 256^2)
  gemm8<1><<<256, 512, 131072, stream>>>(attnout, wob, nullptr, nullptr,
                                         nullptr, nullptr, nullptr, out, nullptr);
}

// Round 8
// 521.308 us; speedup vs baseline: 1.8273x; 1.1507x over previous
//
#include <hip/hip_runtime.h>
#include <hip/hip_bf16.h>

typedef __attribute__((ext_vector_type(4))) float f32x4;
typedef __attribute__((ext_vector_type(8))) short s16x8;

#define SEQ 2048
#define DM  2048
#define NH  16
#define HD  128

__device__ __forceinline__ unsigned short f2b(float f){
  unsigned int u = __builtin_bit_cast(unsigned int, f);
  u += 0x7fffu + ((u >> 16) & 1u);
  return (unsigned short)(u >> 16);
}
__device__ __forceinline__ float b2f(unsigned short h){
  unsigned int u = ((unsigned int)h) << 16;
  return __builtin_bit_cast(float, u);
}
__device__ __forceinline__ f32x4 mfma16(s16x8 a, s16x8 b, f32x4 c){
  return __builtin_amdgcn_mfma_f32_16x16x32_bf16(a, b, c, 0, 0, 0);
}

// ---------------------------------------------------------------------------
// One-shot f32 -> bf16 conversion: x -> xb, [wq|wk|wv] -> wfused, wo -> wob.
// ---------------------------------------------------------------------------
__global__ __launch_bounds__(256)
void convert_kernel(const float* __restrict__ x,  const float* __restrict__ wq,
                    const float* __restrict__ wk, const float* __restrict__ wv,
                    const float* __restrict__ wo,
                    unsigned short* __restrict__ xb,
                    unsigned short* __restrict__ wfused,
                    unsigned short* __restrict__ wob)
{
  size_t e = ((size_t)blockIdx.x * 256 + threadIdx.x) * 8;
  const float* src; unsigned short* dst;
  if (e < 16777216){ src = x + e; dst = xb + e; }
  else if (e < 29360128){
    size_t o = e - 16777216;
    int sel = (int)(o >> 22);
    const float* w = sel == 0 ? wq : (sel == 1 ? wk : wv);
    src = w + (o & 4194303); dst = wfused + o;
  } else {
    size_t o = e - 29360128;
    src = wo + o; dst = wob + o;
  }
  float4 a = ((const float4*)src)[0];
  float4 b = ((const float4*)src)[1];
  s16x8 v;
  v[0]=(short)f2b(a.x); v[1]=(short)f2b(a.y); v[2]=(short)f2b(a.z); v[3]=(short)f2b(a.w);
  v[4]=(short)f2b(b.x); v[5]=(short)f2b(b.y); v[6]=(short)f2b(b.z); v[7]=(short)f2b(b.w);
  *(s16x8*)dst = v;
}

// ---------------------------------------------------------------------------
// Ring-4 GEMM: 256x256 tile, BK=32, 64 K-tiles, 8 waves (2Mx4N).
// LDS = 4 slots x 32KB (A 16K + B 16K), prefetch 3 tiles deep, ONE raw
// s_barrier + counted vmcnt(8) per tile (4/0 at tails). Compiler handles
// lgkmcnt for ds_read->MFMA. Involutive XOR swizzle both sides.
// L2 policy: XCD x owns fixed nb strip (B-panels L2-resident).
// ---------------------------------------------------------------------------
template<int MODE>
__global__ __launch_bounds__(512, 1)
void gemm8(const unsigned short* __restrict__ A,
           const unsigned short* __restrict__ B,
           unsigned short* __restrict__ qr, unsigned short* __restrict__ kr,
           float* __restrict__ koutf,
           float* __restrict__ voutf, unsigned short* __restrict__ vt,
           float* __restrict__ outf, const int* __restrict__ sp)
{
  extern __shared__ char lds[];
  const int tid  = threadIdx.x;
  const int lane = tid & 63;
  const int w    = tid >> 6;           // 0..7
  const int wr   = w >> 2;             // 0..1  (M half)
  const int wc   = w & 3;              // 0..3  (N quarter)
  const int l15  = lane & 15;
  const int lhi  = lane >> 4;          // 0..3
  const int rq   = lhi << 2;

  // XCD-resident B-strips: MODE0 nb = 3x + j%3, MODE1 nb = x.
  int bid = blockIdx.x;
  int x8 = bid & 7, j = bid >> 3;
  int mb, nb;
  if (MODE == 0){ nb = 3*x8 + (j % 3); mb = j / 3; }
  else          { nb = x8;             mb = j; }
  const int m0 = mb * 256, n0 = nb * 256;

  const int sp0 = (MODE == 0) ? sp[0] : 0;

  const unsigned short* Abase = A + (size_t)m0 * 2048;
  const unsigned short* Bbase = B + (size_t)n0 * 2048;

  f32x4 accL[4][4] = {};   // M-frags 0-3
  f32x4 accH[4][4] = {};   // M-frags 4-7

  // stage one 16KB operand (256 rows x 32 cols) of tile t into slot offset
  auto STAGE = [&](const unsigned short* gbase, int slotoff, int t){
    #pragma unroll
    for (int r2 = 0; r2 < 2; r2++){
      int p  = r2*8192 + w*1024 + (lane << 4);     // physical LDS offset
      int lo = p ^ (((p >> 7) & 3) << 4);          // logical (involution)
      int row = lo >> 6, colB = lo & 63;
      __builtin_amdgcn_global_load_lds(
        (const __attribute__((address_space(1))) void*)
          (gbase + (size_t)row*2048 + t*32 + (colB >> 1)),
        (__attribute__((address_space(3))) void*)(lds + slotoff + r2*8192 + w*1024),
        16, 0, 0);
    }
  };
  auto LDA = [&](const char* base, int i0, s16x8* dst){
    #pragma unroll
    for (int i = 0; i < 4; i++){
      int row = wr*128 + (i0 + i)*16 + l15;
      int off = row*64 + lhi*16;
      dst[i] = *(const s16x8*)(base + (off ^ (((row >> 1) & 3) << 4)));
    }
  };
  auto LDB = [&](const char* base, s16x8* dst){
    #pragma unroll
    for (int j2 = 0; j2 < 4; j2++){
      int row = wc*64 + j2*16 + l15;
      int off = row*64 + lhi*16;
      dst[j2] = *(const s16x8*)(base + (off ^ (((row >> 1) & 3) << 4)));
    }
  };
  auto MM = [&](s16x8* a, s16x8* b, f32x4 (&ac)[4][4]){
    __builtin_amdgcn_s_setprio(1);
    #pragma unroll
    for (int i = 0; i < 4; i++)
      #pragma unroll
      for (int j2 = 0; j2 < 4; j2++)
        ac[i][j2] = mfma16(a[i], b[j2], ac[i][j2]);
    __builtin_amdgcn_s_setprio(0);
  };

#define TILE(T, ISSUE, VMW) { \
    const int s_ = (T) & 3; \
    const char* base_ = lds + s_*32768; \
    if (ISSUE){ \
      int so_ = (((T)+3) & 3)*32768; \
      STAGE(Abase, so_, (T)+3); \
      STAGE(Bbase, so_+16384, (T)+3); \
    } \
    s16x8 bfr[4], afL[4], afH[4]; \
    LDB(base_+16384, bfr); LDA(base_, 0, afL); LDA(base_, 4, afH); \
    MM(afL, bfr, accL); MM(afH, bfr, accH); \
    asm volatile("s_waitcnt vmcnt(" #VMW ")" ::: "memory"); \
    __builtin_amdgcn_s_barrier(); }

  // ---- prologue: stage tiles 0,1,2; wait tile 0 ----
  STAGE(Abase, 0, 0);      STAGE(Bbase, 16384, 0);
  STAGE(Abase, 32768, 1);  STAGE(Bbase, 49152, 1);
  STAGE(Abase, 65536, 2);  STAGE(Bbase, 81920, 2);
  asm volatile("s_waitcnt vmcnt(8)" ::: "memory");
  __builtin_amdgcn_s_barrier();

  for (int t = 0; t < 61; t++) TILE(t, 1, 8);
  TILE(61, 0, 4);
  TILE(62, 0, 0);
  { // t = 63: last tile, no wait/barrier
    const char* base_ = lds + 3*32768;
    s16x8 bfr[4], afL[4], afH[4];
    LDB(base_+16384, bfr); LDA(base_, 0, afL); LDA(base_, 4, afH);
    MM(afL, bfr, accL); MM(afH, bfr, accH);
  }
#undef TILE

  // ======================= epilogues =======================
  if (MODE == 1){
    #pragma unroll
    for (int h2 = 0; h2 < 2; h2++){
      f32x4 (&ac)[4][4] = h2 ? accH : accL;
      int ibase = h2 * 4;
      #pragma unroll
      for (int i = 0; i < 4; i++)
        #pragma unroll
        for (int r = 0; r < 4; r++){
          int m = m0 + wr*128 + (ibase+i)*16 + rq + r;
          #pragma unroll
          for (int j2 = 0; j2 < 4; j2++)
            outf[(size_t)m*DM + n0 + wc*64 + j2*16 + l15] = ac[i][j2][r];
        }
    }
    return;
  }

  const int b  = m0 >> 11;
  const int s0 = m0 & 2047;

  if (nb < 16){
    // ---- RoPE Q/K epilogue with block-local LDS angle tables ----
    const bool isK = (nb >= 8);
    unsigned short* dqk = isK ? kr : qr;
    const int fbase = (nb & 7) * 128;
    const int odd = lane & 1;

    __syncthreads();   // all K-loop LDS reads done; reuse LDS for tables
    float2* T2 = (float2*)lds;             // [32 s_lo][128 f]
    float2* T1 = (float2*)(lds + 32768);   // [ 8 s_hi][128 f]
    for (int idx = tid; idx < 5120; idx += 512){
      int fl = idx & 127;
      float th = exp2f(-(float)(fbase + fl) * (13.287712379549449f / 1024.0f));
      float sn, cn;
      if (idx < 4096){
        __sincosf((float)(idx >> 7) * th, &sn, &cn);
        T2[idx] = make_float2(cn, sn);
      } else {
        int sh = (idx - 4096) >> 7;
        __sincosf((float)(sp0 + s0 + sh*32) * th, &sn, &cn);
        T1[idx - 4096] = make_float2(cn, sn);
      }
    }
    __syncthreads();

    #pragma unroll
    for (int h2 = 0; h2 < 2; h2++){
      f32x4 (&ac)[4][4] = h2 ? accH : accL;
      int ibase = h2 * 4;
      #pragma unroll
      for (int i = 0; i < 4; i++){
        #pragma unroll
        for (int r = 0; r < 4; r++){
          int srow = wr*128 + (ibase+i)*16 + rq + r;
          int s  = s0 + srow;
          int sh = srow >> 5, sl = srow & 31;
          #pragma unroll
          for (int j2 = 0; j2 < 4; j2++){
            float v  = ac[i][j2][r];
            float vx = __shfl_xor(v, 1);
            int nn_loc = wc*64 + j2*16 + l15;
            int fl = nn_loc >> 1;
            float2 a1 = T1[sh*128 + fl];
            float2 a2 = T2[sl*128 + fl];
            float cn = a1.x*a2.x - a1.y*a2.y;
            float sn = a1.y*a2.x + a1.x*a2.y;
            float x1 = odd ? vx : v;
            float x2 = odd ? v  : vx;
            float ov = odd ? (x1*sn + x2*cn) : (x1*cn - x2*sn);
            int c = fbase + fl + (odd ? 1024 : 0);
            size_t adr = ((size_t)(b*NH + (c >> 7))*SEQ + s)*HD + (c & 127);
            dqk[adr] = f2b(ov);
            if (isK) koutf[adr] = ov;
          }
        }
      }
    }
  } else {
    // ---- V epilogue: vout f32 (B,H,S,hd) + vt bf16 (B,H,hd,S) ----
    #pragma unroll
    for (int h2 = 0; h2 < 2; h2++){
      f32x4 (&ac)[4][4] = h2 ? accH : accL;
      int ibase = h2 * 4;
      #pragma unroll
      for (int i = 0; i < 4; i++){
        int sb = s0 + wr*128 + (ibase+i)*16 + rq;
        #pragma unroll
        for (int j2 = 0; j2 < 4; j2++){
          int d = (nb - 16)*256 + wc*64 + j2*16 + l15;
          int h = d >> 7, dd = d & 127;
          size_t vb = ((size_t)(b*NH + h)*SEQ + sb)*HD + dd;
          #pragma unroll
          for (int r = 0; r < 4; r++)
            voutf[vb + (size_t)r*HD] = ac[i][j2][r];
          ushort4 pk;
          pk.x = f2b(ac[i][j2][0]); pk.y = f2b(ac[i][j2][1]);
          pk.z = f2b(ac[i][j2][2]); pk.w = f2b(ac[i][j2][3]);
          *(ushort4*)(vt + ((size_t)(b*NH + h)*HD + dd)*SEQ + sb) = pk;
        }
      }
    }
  }
}

// ---------------------------------------------------------------------------
// Causal flash attention v4: 4 waves x 16 q-rows, KVBLK=64. Paired q-tiles
// for uniform load. K 64x256B XOR-swz; V^T / P at 144B pitch. Row-sum via
// ones-MFMA; defer-max (THR=8).
// ---------------------------------------------------------------------------
__global__ __launch_bounds__(256)
void attn_kernel(const unsigned short* __restrict__ qr,
                 const unsigned short* __restrict__ kr,
                 const unsigned short* __restrict__ vt,
                 unsigned short* __restrict__ attnout)
{
  const int pair = blockIdx.x;          // 0..15
  const int bh   = blockIdx.y;          // 0..63
  const int tid  = threadIdx.x;
  const int lane = tid & 63;
  const int w    = tid >> 6;

  __shared__ __align__(16) char Klds[64 * 256];    // 16KB
  __shared__ __align__(16) char Vlds[128 * 144];   // 18KB
  __shared__ __align__(16) char Plds[4][16 * 144]; // 9KB

  const int l15 = lane & 15;
  const int lhi = lane >> 4;
  const int rq  = lhi << 2;
  char* pw = &Plds[w][0];

  s16x8 ones;
  #pragma unroll
  for (int i = 0; i < 8; i++) ones[i] = (short)0x3F80;

  const int b = bh >> 4, h = bh & 15;

  for (int ph = 0; ph < 2; ph++){
    const int qtile = ph ? (31 - pair) : pair;
    const int q0w = qtile*64 + w*16;

    s16x8 qf[4];
    const unsigned short* qbase = qr + ((size_t)bh*SEQ + q0w + l15) * HD + lhi*8;
    #pragma unroll
    for (int c = 0; c < 4; c++) qf[c] = *(const s16x8*)(qbase + c*32);

    f32x4 o[8] = {};
    f32x4 osum = {};
    float mrow[4] = {-1e30f,-1e30f,-1e30f,-1e30f};

    const int ntiles = qtile + 1;
    for (int t = 0; t < ntiles; t++){
      const int kv0 = t * 64;
      __syncthreads();
      { // stage K tile (64 x 128 bf16, rows 256B, XOR swz (r&15)<<4)
        int r = tid >> 2, q4 = tid & 3;
        const unsigned short* src = kr + ((size_t)bh*SEQ + kv0 + r) * HD + q4*32;
        int sw = (r & 15) << 4;
        char* drow = Klds + r*256;
        #pragma unroll
        for (int k = 0; k < 4; k++)
          *(s16x8*)(drow + ((q4*64 + k*16) ^ sw)) = *(const s16x8*)(src + k*8);
      }
      { // stage V^T tile (128 d-rows x 64 kv, 144B pitch)
        int r = tid >> 1, h2 = tid & 1;
        const unsigned short* src = vt + ((size_t)bh*HD + r) * SEQ + kv0 + h2*32;
        char* drow = Vlds + r*144 + h2*64;
        #pragma unroll
        for (int k = 0; k < 4; k++)
          *(s16x8*)(drow + k*16) = *(const s16x8*)(src + k*8);
      }
      __syncthreads();

      // ---- S = Q K^T (16 q x 64 kv as four 16x16 tiles) ----
      f32x4 st[4];
      #pragma unroll
      for (int j = 0; j < 4; j++) st[j] = (f32x4){0.f,0.f,0.f,0.f};
      #pragma unroll
      for (int j = 0; j < 4; j++){
        int krw = j*16 + l15;
        int sw  = (krw & 15) << 4;
        #pragma unroll
        for (int c = 0; c < 4; c++){
          s16x8 kf = *(const s16x8*)(Klds + krw*256 + ((c*64 + lhi*16) ^ sw));
          st[j] = mfma16(qf[c], kf, st[j]);
        }
      }

      const float sc = 0.08838834764831845f;
      #pragma unroll
      for (int j = 0; j < 4; j++)
        #pragma unroll
        for (int r = 0; r < 4; r++){
          int qrow = q0w + rq + r;
          int kvc  = kv0 + j*16 + l15;
          st[j][r] = (kvc > qrow) ? -1e30f : st[j][r] * sc;
        }

      float mt[4];
      #pragma unroll
      for (int r = 0; r < 4; r++)
        mt[r] = fmaxf(fmaxf(st[0][r], st[1][r]), fmaxf(st[2][r], st[3][r]));
      #pragma unroll
      for (int mk = 1; mk < 16; mk <<= 1)
        #pragma unroll
        for (int r = 0; r < 4; r++) mt[r] = fmaxf(mt[r], __shfl_xor(mt[r], mk));

      int ok = 1;
      #pragma unroll
      for (int r = 0; r < 4; r++) ok &= (mt[r] <= mrow[r] + 8.0f) ? 1 : 0;
      if (!__all(ok)){
        float al[4];
        #pragma unroll
        for (int r = 0; r < 4; r++){
          float mn = fmaxf(mrow[r], mt[r]);
          al[r] = __expf(mrow[r] - mn);
          mrow[r] = mn;
        }
        #pragma unroll
        for (int c = 0; c < 8; c++)
          #pragma unroll
          for (int r = 0; r < 4; r++) o[c][r] *= al[r];
        #pragma unroll
        for (int r = 0; r < 4; r++) osum[r] *= al[r];
      }

      // ---- P = exp(S - m) -> per-wave LDS (144B pitch) ----
      #pragma unroll
      for (int r = 0; r < 4; r++){
        char* prb = pw + (rq + r)*144;
        #pragma unroll
        for (int j = 0; j < 4; j++){
          float p = __expf(st[j][r] - mrow[r]);
          *(unsigned short*)(prb + (j*16 + l15)*2) = f2b(p);
        }
      }

      asm volatile("s_waitcnt lgkmcnt(0)" ::: "memory");

      // ---- O += P V (two K=32 passes) ----
      #pragma unroll
      for (int ks = 0; ks < 2; ks++){
        s16x8 pa = *(const s16x8*)(pw + l15*144 + ks*64 + lhi*16);
        #pragma unroll
        for (int c = 0; c < 8; c++){
          int d = c*16 + l15;
          s16x8 vf = *(const s16x8*)(Vlds + d*144 + ks*64 + lhi*16);
          o[c] = mfma16(pa, vf, o[c]);
        }
        osum = mfma16(pa, ones, osum);
      }
    }

    #pragma unroll
    for (int r = 0; r < 4; r++){
      float inv = 1.0f / osum[r];
      int s2 = q0w + rq + r;
      size_t base = ((size_t)(b*SEQ + s2)) * DM + h*HD;
      #pragma unroll
      for (int c = 0; c < 8; c++)
        attnout[base + c*16 + l15] = f2b(o[c][r] * inv);
    }
  }
}

// ---------------------------------------------------------------------------
extern "C" void kernel_launch(void* const* d_in, const int* in_sizes, int n_in,
                              void* d_out, int out_size, void* d_ws, size_t ws_size,
                              hipStream_t stream)
{
  const float* x  = (const float*)d_in[0];
  const float* wq = (const float*)d_in[1];
  const float* wk = (const float*)d_in[2];
  const float* wv = (const float*)d_in[3];
  const float* wo = (const float*)d_in[4];
  const int*   sp = (const int*)d_in[5];

  float* out  = (float*)d_out;            // (B,S,D) f32
  float* kout = out + 16777216;           // (B,H,S,hd) f32
  float* vout = out + 33554432;           // (B,H,S,hd) f32

  char* ws = (char*)d_ws;
  unsigned short* xb      = (unsigned short*)ws;                  // 8192x2048 bf16
  unsigned short* wfused  = (unsigned short*)(ws + 33554432);     // 6144x2048 bf16
  unsigned short* wob     = (unsigned short*)(ws + 58720256);     // 2048x2048 bf16
  unsigned short* qr      = (unsigned short*)(ws + 67108864);     // (B,H,S,hd) bf16
  unsigned short* kr      = (unsigned short*)(ws + 100663296);    // (B,H,S,hd) bf16
  unsigned short* vt      = (unsigned short*)(ws + 134217728);    // (B,H,hd,S) bf16
  unsigned short* attnout = (unsigned short*)ws;                  // alias xb

  hipFuncSetAttribute((const void*)gemm8<0>,
                      hipFuncAttributeMaxDynamicSharedMemorySize, 131072);
  hipFuncSetAttribute((const void*)gemm8<1>,
                      hipFuncAttributeMaxDynamicSharedMemorySize, 131072);

  // 1) f32 -> bf16 conversion
  convert_kernel<<<16384, 256, 0, stream>>>(x, wq, wk, wv, wo, xb, wfused, wob);
  // 2) fused QKV GEMM (ring-4, XCD-resident B strips)
  gemm8<0><<<768, 512, 131072, stream>>>(xb, wfused, qr, kr, kout,
                                         vout, vt, nullptr, sp);
  // 3) causal flash attention (KVBLK=64, paired q-tiles)
  attn_kernel<<<dim3(16, 64), 256, 0, stream>>>(qr, kr, vt, attnout);
  // 4) output GEMM (ring-4)
  gemm8<1><<<256, 512, 131072, stream>>>(attnout, wob, nullptr, nullptr,
                                         nullptr, nullptr, nullptr, out, nullptr);
}